// Round 6
// baseline (1243.781 us; speedup 1.0000x reference)
//
#include <hip/hip_runtime.h>

#define NS   50000
#define LSEQ 32
#define IND  64
#define HIDN 64
#define OUTD 128
#define NR   11
#define SB   64          // samples per K1 block

using bf16x8  = __attribute__((ext_vector_type(8))) short;
using f32x16  = __attribute__((ext_vector_type(16))) float;

union U8 { bf16x8 v; unsigned u[4]; uint2 d[2]; };

__device__ __forceinline__ unsigned cvt_pk_bf16(float a, float b) {
  unsigned r;
  asm volatile("v_cvt_pk_bf16_f32 %0, %1, %2" : "=v"(r) : "v"(a), "v"(b));
  return r;  // r[15:0] = bf16(a), r[31:16] = bf16(b)
}
__device__ __forceinline__ float fsig(float x) {
  return __builtin_amdgcn_rcpf(1.f + __expf(-x));
}
__device__ __forceinline__ float ftanh_(float x) {
  return 1.f - 2.f * __builtin_amdgcn_rcpf(__expf(2.f * x) + 1.f);
}
__device__ __forceinline__ void gload_lds16(const void* g, void* l) {
  __builtin_amdgcn_global_load_lds(
      (const __attribute__((address_space(1))) unsigned*)g,
      (__attribute__((address_space(3))) unsigned*)l, 16, 0, 0);
}

// ---------------- feature table -> bf16 (halves gather traffic) ------------
__global__ __launch_bounds__(256) void fprep_kernel(
    const float* __restrict__ f, unsigned* __restrict__ fb) {
  int i = blockIdx.x * 256 + threadIdx.x;      // uint index (2 floats)
  if (i < NS * IND / 2) {
    float2 v = ((const float2*)f)[i];
    fb[i] = cvt_pk_bf16(v.x, v.y);
  }
}

// ---------------- length sort (descending), LDS-binned ---------------------
__global__ void zero_cnt_kernel(int* cnt) {
  if (threadIdx.x < 64) cnt[threadIdx.x] = 0;  // cnt[32] + cur[32]
}
__global__ __launch_bounds__(256) void hist_kernel(
    const int* __restrict__ lens, int* __restrict__ cnt) {
  __shared__ int lc[32];
  int t = threadIdx.x;
  if (t < 32) lc[t] = 0;
  __syncthreads();
  int s = blockIdx.x * 256 + t;
  if (s < NS) atomicAdd(&lc[32 - lens[s]], 1);
  __syncthreads();
  if (t < 32 && lc[t]) atomicAdd(&cnt[t], lc[t]);
}
__global__ void prefix_kernel(const int* __restrict__ cnt, int* __restrict__ cur) {
  if (threadIdx.x == 0) {
    int sum = 0;
    for (int b = 0; b < 32; ++b) { cur[b] = sum; sum += cnt[b]; }
  }
}
__global__ __launch_bounds__(256) void scatter_kernel(
    const int* __restrict__ lens, int* __restrict__ cur, int* __restrict__ ord) {
  __shared__ int lc[32], lb[32];
  int t = threadIdx.x;
  if (t < 32) lc[t] = 0;
  __syncthreads();
  int s = blockIdx.x * 256 + t;
  int rank = 0, bin = 0;
  if (s < NS) {
    bin = 32 - lens[s];
    rank = atomicAdd(&lc[bin], 1);      // LDS atomic (fast)
  }
  __syncthreads();
  if (t < 32 && lc[t]) lb[t] = atomicAdd(&cur[t], lc[t]);  // 32/block global
  __syncthreads();
  if (s < NS) ord[lb[bin] + rank] = s;
}

// ---------------------------------------------------------------------------
// K1: fused gather + bf16-MFMA LSTM + relation pooling, length-sorted blocks.
// 1024 thr / 16 waves / 64 samples. Wave w = (row-group w>>1, col-tile w&1):
// row-group owns 32 gate-permuted z-rows (8 units), col-tile picks 32 samples.
// Per-block steps = block-max length; 2-deep prefetch; 1 barrier per step;
// double-buffered XOR-swizzled activation tile. Halves block-halfstep count
// vs the 32-sample variant while keeping per-lane state identical.
// ---------------------------------------------------------------------------
__global__ __launch_bounds__(1024, 8) void lstm_mfma_kernel(
    const unsigned* __restrict__ fb, const int* __restrict__ nbr,
    const int* __restrict__ lens, const int* __restrict__ rels,
    const float* __restrict__ adjw, const float* __restrict__ Wih,
    const float* __restrict__ Whh, const int* __restrict__ ord,
    unsigned* __restrict__ phi, unsigned* __restrict__ plo,
    int s0, int cnt)
{
  __shared__ short xh[2 * SB * 128];   // 32KB: 2 x [64 samp][128 k] bf16, swizzled
  __shared__ float sh_w[SB][33];
  __shared__ int   sh_meta[SB][33];    // rel<<16 | nbr (nbr < 2^16)
  __shared__ int   sh_len[SB];

  const int tid   = threadIdx.x;
  const int lane  = tid & 63;
  const int w     = tid >> 6;          // 0..15
  const int sbase = blockIdx.x * SB;

  for (int i = tid; i < SB * 32; i += 1024) {
    int ss = i >> 5, l = i & 31;
    int gp = sbase + ss;
    bool ok = gp < cnt;
    int gs = ok ? ord[s0 + gp] : 0;
    size_t off = (size_t)gs * LSEQ + l;
    sh_w[ss][l]    = ok ? adjw[off] : 0.f;
    sh_meta[ss][l] = ok ? ((rels[off] << 16) | nbr[off]) : 0;
  }
  if (tid < SB) {
    int gp = sbase + tid;
    sh_len[tid] = (gp < cnt) ? lens[ord[s0 + gp]] : 0;
  }
  for (int i = tid; i < 2 * SB * 128; i += 1024) xh[i] = 0;

  // stationary A fragments (gate-permuted weight rows, bf16); row-group w>>1
  bf16x8 Af[8];
  {
    const int rr = lane & 31, kh = lane >> 5;
    const int g = rr & 3, q = rr >> 2;
    const int u = (w >> 1) * 8 + 4 * (q & 1) + (q >> 1);
    const int row = g * 64 + u;
#pragma unroll
    for (int kc = 0; kc < 8; ++kc) {
      int k0 = kc * 16 + kh * 8;
      const float* src = (k0 < 64) ? (Wih + row * 64 + k0)
                                   : (Whh + row * 64 + (k0 - 64));
      float4 f0 = *(const float4*)(src);
      float4 f1 = *(const float4*)(src + 4);
      U8 a;
      a.u[0] = cvt_pk_bf16(f0.x, f0.y); a.u[1] = cvt_pk_bf16(f0.z, f0.w);
      a.u[2] = cvt_pk_bf16(f1.x, f1.y); a.u[3] = cvt_pk_bf16(f1.z, f1.w);
      Af[kc] = a.v;
    }
  }

  const int s    = (w & 1) * 32 + (lane & 31);  // gate-phase / B-tile sample
  const int hi   = lane >> 5;
  const int sxor = (s & 15) << 4;
  const int u0   = (w >> 1) * 8 + 4 * hi;       // 4 consecutive units
  const int hoff = s * 128 + (((128 + u0 * 2) ^ sxor) >> 1);   // short idx
  const int gsamp = tid >> 4, gseg = tid & 15;                 // gather role
  const int goff  = gsamp * 128 + (((gseg * 8) ^ ((gsamp & 15) << 4)) >> 1);

  float c4[4] = {0.f, 0.f, 0.f, 0.f};
  float pooled[4][NR] = {};

  __syncthreads();
  const int len_s = sh_len[s];
  const int len_g = sh_len[gsamp];
  const int tmax  = (sh_len[0] + 1) & ~1;   // block max (descending sort), even

  {  // prologue: x_0 -> buf0 (bf16 row, uint2 per lane)
    uint2 xv = make_uint2(0u, 0u);
    if (0 < len_g) {
      int nid = sh_meta[gsamp][0] & 0xffff;
      xv = *(const uint2*)(fb + (size_t)nid * 32 + gseg * 2);
    }
    *(uint2*)&xh[goff] = xv;
  }
  uint2 xA = make_uint2(0u, 0u), xB;
  if (1 < len_g) {
    int nid = sh_meta[gsamp][1] & 0xffff;
    xA = *(const uint2*)(fb + (size_t)nid * 32 + gseg * 2);
  }
  __syncthreads();

#define HALFSTEP(bufR, bufW, XLOAD, XWRITE, tc)                              \
  {                                                                          \
    uint2 xn = make_uint2(0u, 0u);                                           \
    if ((tc) + 2 < len_g) {                                                  \
      int nid = sh_meta[gsamp][(tc) + 2] & 0xffff;                           \
      xn = *(const uint2*)(fb + (size_t)nid * 32 + gseg * 2);                \
    }                                                                        \
    XLOAD = xn;                                                              \
    f32x16 acc = {};                                                         \
    __builtin_amdgcn_s_setprio(1);                                           \
    _Pragma("unroll")                                                        \
    for (int kc = 0; kc < 8; ++kc) {                                         \
      int roff = s * 128 + (((kc * 32 + hi * 16) ^ sxor) >> 1);              \
      bf16x8 b = *(const bf16x8*)(&xh[(bufR) + roff]);                       \
      acc = __builtin_amdgcn_mfma_f32_32x32x16_bf16(Af[kc], b, acc, 0, 0, 0);\
    }                                                                        \
    __builtin_amdgcn_s_setprio(0);                                           \
    int pk = sh_meta[s][tc];                                                 \
    float wv = ((tc) < len_s) ? sh_w[s][tc] : 0.f;                           \
    int rl = pk >> 16;                                                       \
    float h4[4];                                                             \
    _Pragma("unroll")                                                        \
    for (int p = 0; p < 4; ++p) {                                            \
      float gi = fsig(acc[4 * p + 0]);                                       \
      float gf = fsig(acc[4 * p + 1]);                                       \
      float gg = ftanh_(acc[4 * p + 2]);                                     \
      float go = fsig(acc[4 * p + 3]);                                       \
      float cc = gf * c4[p] + gi * gg;                                       \
      c4[p] = cc;                                                            \
      h4[p] = go * ftanh_(cc);                                               \
    }                                                                        \
    _Pragma("unroll")                                                        \
    for (int r = 0; r < NR; ++r) {                                           \
      float mr = (rl == r) ? wv : 0.f;                                       \
      pooled[0][r] += mr * h4[0]; pooled[1][r] += mr * h4[1];                \
      pooled[2][r] += mr * h4[2]; pooled[3][r] += mr * h4[3];                \
    }                                                                        \
    *(uint2*)&xh[(bufW) + hoff] = make_uint2(cvt_pk_bf16(h4[0], h4[1]),      \
                                             cvt_pk_bf16(h4[2], h4[3]));     \
    *(uint2*)&xh[(bufW) + goff] = XWRITE;                                    \
    __syncthreads();                                                         \
  }

#pragma unroll 1
  for (int t = 0; t < tmax; t += 2) {
    HALFSTEP(0,    8192, xB, xA, t)
    HALFSTEP(8192, 0,    xA, xB, t + 1)
  }
#undef HALFSTEP

  // pooled -> hi/lo bf16 planes: [sorted-pos][11][64] bf16 each
  if (sbase + s < cnt) {
    size_t base = ((size_t)(sbase + s) * NR) * 32;
#pragma unroll
    for (int r = 0; r < NR; ++r) {
      float p0 = pooled[0][r], p1 = pooled[1][r];
      float p2 = pooled[2][r], p3 = pooled[3][r];
      unsigned h0 = cvt_pk_bf16(p0, p1), h1 = cvt_pk_bf16(p2, p3);
      float l0 = p0 - __uint_as_float(h0 << 16);
      float l1 = p1 - __uint_as_float(h0 & 0xffff0000u);
      float l2 = p2 - __uint_as_float(h1 << 16);
      float l3 = p3 - __uint_as_float(h1 & 0xffff0000u);
      unsigned g0 = cvt_pk_bf16(l0, l1), g1 = cvt_pk_bf16(l2, l3);
      *(uint2*)&phi[base + r * 32 + (u0 >> 1)] = make_uint2(h0, h1);
      *(uint2*)&plo[base + r * 32 + (u0 >> 1)] = make_uint2(g0, g1);
    }
  }
}

// ---------------------------------------------------------------------------
// Prep: Wr[11][64][128] f32 -> wt[r]: [hi 16KB | lo 16KB], each [128 o][64 k]
// bf16 with baked 4-bit XOR swizzle (byte ^= (o&15)<<3) for conflict-free b64.
// ---------------------------------------------------------------------------
__global__ __launch_bounds__(256) void wprep_kernel(
    const float* __restrict__ Wr, unsigned* __restrict__ wt)
{
  __shared__ float wl[64 * 128];
  const int r = blockIdx.x;
  for (int i = threadIdx.x; i < 64 * 128; i += 256)
    wl[i] = Wr[r * 64 * 128 + i];
  __syncthreads();
  const int o = threadIdx.x >> 1, kb = (threadIdx.x & 1) * 32;
  const int sw = (o & 15) << 3;
  unsigned* hip = wt + r * 8192;
  unsigned* lop = hip + 4096;
  for (int k = kb; k < kb + 32; k += 2) {
    float f0 = wl[k * 128 + o], f1 = wl[(k + 1) * 128 + o];
    unsigned h = cvt_pk_bf16(f0, f1);
    float l0 = f0 - __uint_as_float(h << 16);
    float l1 = f1 - __uint_as_float(h & 0xffff0000u);
    unsigned l = cvt_pk_bf16(l0, l1);
    int byte = o * 128 + ((k * 2) ^ sw);
    hip[byte >> 2] = h;
    lop[byte >> 2] = l;
  }
}

// ---------------------------------------------------------------------------
// K2: proj = sum_r pooled_r @ W_r via split-bf16 MFMA (hi*hi + hi*lo + lo*hi),
// D[m=out][n=samp]; atomic scatter to out[nodes]. 256 thr / 4 waves / 64 samp.
// ---------------------------------------------------------------------------
__global__ __launch_bounds__(256, 4) void rgc_mfma_kernel(
    const unsigned* __restrict__ wt, const unsigned* __restrict__ phi,
    const unsigned* __restrict__ plo, const int* __restrict__ nodes,
    const int* __restrict__ ord, float* __restrict__ out, int s0, int cnt)
{
  __shared__ short wl[2 * 8192];   // 32KB: W hi | lo tile for current r
  const int tid = threadIdx.x, lane = tid & 63, nt = tid >> 6;
  const int l31 = lane & 31, lhi = lane >> 5;
  const int sbase = blockIdx.x * 64;

  const int row = nt * 32 + l31;            // wT row = out index
  const int rsw = (row & 15) << 3;
  int aoff[8];
#pragma unroll
  for (int kc = 0; kc < 4; ++kc)
#pragma unroll
    for (int hf = 0; hf < 2; ++hf)
      aoff[kc * 2 + hf] = row * 64 + (((kc * 32 + lhi * 16 + hf * 8) ^ rsw) >> 1);

  f32x16 acc0 = {}, acc1 = {};

  for (int r = 0; r < NR; ++r) {
    __syncthreads();
    {
      const char* src = (const char*)(wt + r * 8192);
#pragma unroll
      for (int i = 0; i < 8; ++i) {
        int off = (i * 4 + nt) * 1024 + lane * 16;
        gload_lds16(src + off, (char*)wl + off);
      }
    }
    __syncthreads();

    bf16x8 ahi[4], alo[4];
#pragma unroll
    for (int kc = 0; kc < 4; ++kc) {
      U8 a, b;
      a.d[0] = *(const uint2*)&wl[aoff[kc * 2 + 0]];
      a.d[1] = *(const uint2*)&wl[aoff[kc * 2 + 1]];
      b.d[0] = *(const uint2*)&wl[8192 + aoff[kc * 2 + 0]];
      b.d[1] = *(const uint2*)&wl[8192 + aoff[kc * 2 + 1]];
      ahi[kc] = a.v; alo[kc] = b.v;
    }

#pragma unroll
    for (int st = 0; st < 2; ++st) {
      f32x16& accr = st ? acc1 : acc0;
      int samp = sbase + st * 32 + l31;
      size_t bb = ((size_t)samp * NR + r) * 32 + lhi * 4;
#pragma unroll
      for (int kc = 0; kc < 4; ++kc) {
        U8 bh, bl;
        *(uint4*)bh.u = *(const uint4*)&phi[bb + kc * 8];
        *(uint4*)bl.u = *(const uint4*)&plo[bb + kc * 8];
        accr = __builtin_amdgcn_mfma_f32_32x32x16_bf16(ahi[kc], bh.v, accr, 0, 0, 0);
        accr = __builtin_amdgcn_mfma_f32_32x32x16_bf16(ahi[kc], bl.v, accr, 0, 0, 0);
        accr = __builtin_amdgcn_mfma_f32_32x32x16_bf16(alo[kc], bh.v, accr, 0, 0, 0);
      }
    }
  }

#pragma unroll
  for (int st = 0; st < 2; ++st) {
    int sl = sbase + st * 32 + l31;
    if (sl < cnt) {
      int nd = nodes[ord[s0 + sl]];
      float* dst = out + (size_t)nd * OUTD + nt * 32;
      const f32x16& a = st ? acc1 : acc0;
#pragma unroll
      for (int j = 0; j < 16; ++j) {
        int m = (j & 3) + 8 * (j >> 2) + 4 * lhi;
        atomicAdd(dst + m, a[j]);
      }
    }
  }
}

__global__ void relu_kernel(float4* __restrict__ out, int n4) {
  int i = blockIdx.x * 256 + threadIdx.x;
  if (i < n4) {
    float4 v = out[i];
    v.x = fmaxf(v.x, 0.f); v.y = fmaxf(v.y, 0.f);
    v.z = fmaxf(v.z, 0.f); v.w = fmaxf(v.w, 0.f);
    out[i] = v;
  }
}

extern "C" void kernel_launch(void* const* d_in, const int* in_sizes, int n_in,
                              void* d_out, int out_size, void* d_ws, size_t ws_size,
                              hipStream_t stream) {
  const int*   nbr   = (const int*)d_in[0];
  const int*   lens  = (const int*)d_in[1];
  const int*   rels  = (const int*)d_in[2];
  const int*   nodes = (const int*)d_in[3];
  const float* adjw  = (const float*)d_in[4];
  const float* feat  = (const float*)d_in[5];
  const float* Wih   = (const float*)d_in[6];
  const float* Whh   = (const float*)d_in[7];
  const float* Wr    = (const float*)d_in[8];
  float* out = (float*)d_out;

  hipMemsetAsync(d_out, 0, (size_t)NS * OUTD * sizeof(float), stream);

  // ws layout: wt [0,360448) | fb bf16 feat [360448, 6760448) |
  //            ord [6760448, 6960448) | cnt/cur [6960448, +256) | phi/plo
  unsigned* wt  = (unsigned*)d_ws;
  unsigned* fb  = (unsigned*)((char*)d_ws + 360448);
  int*      ord = (int*)((char*)d_ws + 6760448);
  int*      cnt = (int*)((char*)d_ws + 6960448);
  int*      cur = cnt + 32;
  const size_t PHI_OFF = 6960768;
  unsigned* phi = (unsigned*)((char*)d_ws + PHI_OFF);

  wprep_kernel<<<NR, 256, 0, stream>>>(Wr, wt);
  fprep_kernel<<<(NS * IND / 2 + 255) / 256, 256, 0, stream>>>(feat, fb);
  zero_cnt_kernel<<<1, 64, 0, stream>>>(cnt);
  hist_kernel<<<(NS + 255) / 256, 256, 0, stream>>>(lens, cnt);
  prefix_kernel<<<1, 64, 0, stream>>>(cnt, cur);
  scatter_kernel<<<(NS + 255) / 256, 256, 0, stream>>>(lens, cur, ord);

  size_t avail = (ws_size > PHI_OFF) ? ws_size - PHI_OFF : 0;
  long long cap = (long long)(avail / 2816);     // samples (1408B x 2 planes)
  long long ch = cap - 64;
  ch &= ~63LL;
  if (ch > NS) ch = NS;
  if (ch < 64) ch = 64;
  unsigned* plo = phi + (size_t)cap * 352;       // 352 u32 = 1408B per sample

  for (int s0 = 0; s0 < NS; s0 += (int)ch) {
    int cnt_c = (NS - s0 < (int)ch) ? (NS - s0) : (int)ch;
    lstm_mfma_kernel<<<(cnt_c + SB - 1) / SB, 1024, 0, stream>>>(
        fb, nbr, lens, rels, adjw, Wih, Whh, ord, phi, plo, s0, cnt_c);
    rgc_mfma_kernel<<<(cnt_c + 63) / 64, 256, 0, stream>>>(
        wt, phi, plo, nodes, ord, out, s0, cnt_c);
  }
  relu_kernel<<<(NS * OUTD / 4 + 255) / 256, 256, 0, stream>>>(
      (float4*)out, NS * OUTD / 4);
}

// Round 7
// 1046.523 us; speedup vs baseline: 1.1885x; 1.1885x over previous
//
#include <hip/hip_runtime.h>

#define NS   50000
#define LSEQ 32
#define IND  64
#define HIDN 64
#define OUTD 128
#define NR   11

using bf16x8  = __attribute__((ext_vector_type(8))) short;
using f32x16  = __attribute__((ext_vector_type(16))) float;

union U8 { bf16x8 v; unsigned u[4]; uint2 d[2]; };

__device__ __forceinline__ unsigned cvt_pk_bf16(float a, float b) {
  unsigned r;
  asm volatile("v_cvt_pk_bf16_f32 %0, %1, %2" : "=v"(r) : "v"(a), "v"(b));
  return r;  // r[15:0] = bf16(a), r[31:16] = bf16(b)
}
__device__ __forceinline__ float fsig(float x) {
  return __builtin_amdgcn_rcpf(1.f + __expf(-x));
}
__device__ __forceinline__ float ftanh_(float x) {
  return 1.f - 2.f * __builtin_amdgcn_rcpf(__expf(2.f * x) + 1.f);
}
__device__ __forceinline__ void gload_lds16(const void* g, void* l) {
  __builtin_amdgcn_global_load_lds(
      (const __attribute__((address_space(1))) unsigned*)g,
      (__attribute__((address_space(3))) unsigned*)l, 16, 0, 0);
}

// ---------------- feature table -> bf16 (halves gather traffic) ------------
__global__ __launch_bounds__(256) void fprep_kernel(
    const float* __restrict__ f, unsigned* __restrict__ fb) {
  int i = blockIdx.x * 256 + threadIdx.x;      // uint index (2 floats)
  if (i < NS * IND / 2) {
    float2 v = ((const float2*)f)[i];
    fb[i] = cvt_pk_bf16(v.x, v.y);
  }
}

// ---------------- length sort (descending), LDS-binned ---------------------
__global__ void zero_cnt_kernel(int* cnt) {
  if (threadIdx.x < 64) cnt[threadIdx.x] = 0;  // cnt[32] + cur[32]
}
__global__ __launch_bounds__(256) void hist_kernel(
    const int* __restrict__ lens, int* __restrict__ cnt) {
  __shared__ int lc[32];
  int t = threadIdx.x;
  if (t < 32) lc[t] = 0;
  __syncthreads();
  int s = blockIdx.x * 256 + t;
  if (s < NS) atomicAdd(&lc[32 - lens[s]], 1);
  __syncthreads();
  if (t < 32 && lc[t]) atomicAdd(&cnt[t], lc[t]);
}
__global__ void prefix_kernel(const int* __restrict__ cnt, int* __restrict__ cur) {
  if (threadIdx.x == 0) {
    int sum = 0;
    for (int b = 0; b < 32; ++b) { cur[b] = sum; sum += cnt[b]; }
  }
}
__global__ __launch_bounds__(256) void scatter_kernel(
    const int* __restrict__ lens, int* __restrict__ cur, int* __restrict__ ord) {
  __shared__ int lc[32], lb[32];
  int t = threadIdx.x;
  if (t < 32) lc[t] = 0;
  __syncthreads();
  int s = blockIdx.x * 256 + t;
  int rank = 0, bin = 0;
  if (s < NS) {
    bin = 32 - lens[s];
    rank = atomicAdd(&lc[bin], 1);      // LDS atomic (fast)
  }
  __syncthreads();
  if (t < 32 && lc[t]) lb[t] = atomicAdd(&cur[t], lc[t]);  // 32/block global
  __syncthreads();
  if (s < NS) ord[lb[bin] + rank] = s;
}

// ---------------------------------------------------------------------------
// K1: fused gather + bf16-MFMA LSTM + relation pooling, length-sorted blocks.
// 512 thr / 8 waves / 32 samples; (512,6) -> 3 blocks/CU for latency hiding.
// Pooled output written TRANSPOSED: phi_T[r][u_pair][sample] (coalesced both
// on K1 write and K2 read).
// ---------------------------------------------------------------------------
__global__ __launch_bounds__(512, 6) void lstm_mfma_kernel(
    const unsigned* __restrict__ fb, const int* __restrict__ nbr,
    const int* __restrict__ lens, const int* __restrict__ rels,
    const float* __restrict__ adjw, const float* __restrict__ Wih,
    const float* __restrict__ Whh, const int* __restrict__ ord,
    unsigned* __restrict__ phi, unsigned* __restrict__ plo,
    int s0, int cnt, int cap)
{
  __shared__ short xh[2 * 32 * 128];   // 16KB: 2 x [32 samp][128 k] bf16, swizzled
  __shared__ float sh_w[32][33];
  __shared__ int   sh_meta[32][33];    // rel<<16 | nbr (nbr < 2^16)
  __shared__ int   sh_len[32];

  const int tid   = threadIdx.x;
  const int lane  = tid & 63;
  const int w     = tid >> 6;
  const int sbase = blockIdx.x * 32;

  for (int i = tid; i < 32 * 32; i += 512) {
    int ss = i >> 5, l = i & 31;
    int gp = sbase + ss;
    bool ok = gp < cnt;
    int gs = ok ? ord[s0 + gp] : 0;
    size_t off = (size_t)gs * LSEQ + l;
    sh_w[ss][l]    = ok ? adjw[off] : 0.f;
    sh_meta[ss][l] = ok ? ((rels[off] << 16) | nbr[off]) : 0;
  }
  if (tid < 32) {
    int gp = sbase + tid;
    sh_len[tid] = (gp < cnt) ? lens[ord[s0 + gp]] : 0;
  }
  for (int i = tid; i < 2 * 32 * 128; i += 512) xh[i] = 0;

  // stationary A fragments (gate-permuted weight rows, bf16)
  bf16x8 Af[8];
  {
    const int rr = lane & 31, kh = lane >> 5;
    const int g = rr & 3, q = rr >> 2;
    const int u = w * 8 + 4 * (q & 1) + (q >> 1);
    const int row = g * 64 + u;
#pragma unroll
    for (int kc = 0; kc < 8; ++kc) {
      int k0 = kc * 16 + kh * 8;
      const float* src = (k0 < 64) ? (Wih + row * 64 + k0)
                                   : (Whh + row * 64 + (k0 - 64));
      float4 f0 = *(const float4*)(src);
      float4 f1 = *(const float4*)(src + 4);
      U8 a;
      a.u[0] = cvt_pk_bf16(f0.x, f0.y); a.u[1] = cvt_pk_bf16(f0.z, f0.w);
      a.u[2] = cvt_pk_bf16(f1.x, f1.y); a.u[3] = cvt_pk_bf16(f1.z, f1.w);
      Af[kc] = a.v;
    }
  }

  const int s    = lane & 31;          // gate-phase sample
  const int hi   = lane >> 5;
  const int sxor = (s & 15) << 4;
  const int u0   = w * 8 + 4 * hi;     // 4 consecutive units
  const int hoff = s * 128 + (((128 + u0 * 2) ^ sxor) >> 1);   // short idx
  const int gsamp = tid >> 4, gseg = tid & 15;                 // gather role
  const int goff  = gsamp * 128 + (((gseg * 8) ^ ((gsamp & 15) << 4)) >> 1);

  float c4[4] = {0.f, 0.f, 0.f, 0.f};
  float pooled[4][NR] = {};

  __syncthreads();
  const int len_s = sh_len[s];
  const int len_g = sh_len[gsamp];
  const int tmax  = (sh_len[0] + 1) & ~1;   // block max (descending sort), even

  {  // prologue: x_0 -> buf0 (bf16 row, uint2 per lane)
    uint2 xv = make_uint2(0u, 0u);
    if (0 < len_g) {
      int nid = sh_meta[gsamp][0] & 0xffff;
      xv = *(const uint2*)(fb + (size_t)nid * 32 + gseg * 2);
    }
    *(uint2*)&xh[goff] = xv;
  }
  uint2 xA = make_uint2(0u, 0u), xB;
  if (1 < len_g) {
    int nid = sh_meta[gsamp][1] & 0xffff;
    xA = *(const uint2*)(fb + (size_t)nid * 32 + gseg * 2);
  }
  __syncthreads();

#define HALFSTEP(bufR, bufW, XLOAD, XWRITE, tc)                              \
  {                                                                          \
    uint2 xn = make_uint2(0u, 0u);                                           \
    if ((tc) + 2 < len_g) {                                                  \
      int nid = sh_meta[gsamp][(tc) + 2] & 0xffff;                           \
      xn = *(const uint2*)(fb + (size_t)nid * 32 + gseg * 2);                \
    }                                                                        \
    XLOAD = xn;                                                              \
    f32x16 acc = {};                                                         \
    _Pragma("unroll")                                                        \
    for (int kc = 0; kc < 8; ++kc) {                                         \
      int roff = s * 128 + (((kc * 32 + hi * 16) ^ sxor) >> 1);              \
      bf16x8 b = *(const bf16x8*)(&xh[(bufR) + roff]);                       \
      acc = __builtin_amdgcn_mfma_f32_32x32x16_bf16(Af[kc], b, acc, 0, 0, 0);\
    }                                                                        \
    int pk = sh_meta[s][tc];                                                 \
    float wv = ((tc) < len_s) ? sh_w[s][tc] : 0.f;                           \
    int rl = pk >> 16;                                                       \
    float h4[4];                                                             \
    _Pragma("unroll")                                                        \
    for (int p = 0; p < 4; ++p) {                                            \
      float gi = fsig(acc[4 * p + 0]);                                       \
      float gf = fsig(acc[4 * p + 1]);                                       \
      float gg = ftanh_(acc[4 * p + 2]);                                     \
      float go = fsig(acc[4 * p + 3]);                                       \
      float cc = gf * c4[p] + gi * gg;                                       \
      c4[p] = cc;                                                            \
      h4[p] = go * ftanh_(cc);                                               \
    }                                                                        \
    _Pragma("unroll")                                                        \
    for (int r = 0; r < NR; ++r) {                                           \
      float mr = (rl == r) ? wv : 0.f;                                       \
      pooled[0][r] += mr * h4[0]; pooled[1][r] += mr * h4[1];                \
      pooled[2][r] += mr * h4[2]; pooled[3][r] += mr * h4[3];                \
    }                                                                        \
    *(uint2*)&xh[(bufW) + hoff] = make_uint2(cvt_pk_bf16(h4[0], h4[1]),      \
                                             cvt_pk_bf16(h4[2], h4[3]));     \
    *(uint2*)&xh[(bufW) + goff] = XWRITE;                                    \
    __syncthreads();                                                         \
  }

#pragma unroll 1
  for (int t = 0; t < tmax; t += 2) {
    HALFSTEP(0,    4096, xB, xA, t)
    HALFSTEP(4096, 0,    xA, xB, t + 1)
  }
#undef HALFSTEP

  // pooled -> TRANSPOSED hi/lo bf16 planes: phi[r*32 + u/2][sample]
  if (sbase + s < cnt) {
    int gpos = sbase + s;
    int up0 = (u0 >> 1);                       // = w*4 + 2*hi
#pragma unroll
    for (int r = 0; r < NR; ++r) {
      float p0 = pooled[0][r], p1 = pooled[1][r];
      float p2 = pooled[2][r], p3 = pooled[3][r];
      unsigned h0 = cvt_pk_bf16(p0, p1), h1 = cvt_pk_bf16(p2, p3);
      float l0 = p0 - __uint_as_float(h0 << 16);
      float l1 = p1 - __uint_as_float(h0 & 0xffff0000u);
      float l2 = p2 - __uint_as_float(h1 << 16);
      float l3 = p3 - __uint_as_float(h1 & 0xffff0000u);
      unsigned g0 = cvt_pk_bf16(l0, l1), g1 = cvt_pk_bf16(l2, l3);
      phi[(size_t)(r * 32 + up0) * cap + gpos]     = h0;
      phi[(size_t)(r * 32 + up0 + 1) * cap + gpos] = h1;
      plo[(size_t)(r * 32 + up0) * cap + gpos]     = g0;
      plo[(size_t)(r * 32 + up0 + 1) * cap + gpos] = g1;
    }
  }
}

// ---------------------------------------------------------------------------
// Prep: Wr[11][64][128] f32 -> wt[r]: [hi 16KB | lo 16KB], each [128 o][64 k]
// bf16 with baked 4-bit XOR swizzle (byte ^= (o&15)<<3) for conflict-free b64.
// ---------------------------------------------------------------------------
__global__ __launch_bounds__(256) void wprep_kernel(
    const float* __restrict__ Wr, unsigned* __restrict__ wt)
{
  __shared__ float wl[64 * 128];
  const int r = blockIdx.x;
  for (int i = threadIdx.x; i < 64 * 128; i += 256)
    wl[i] = Wr[r * 64 * 128 + i];
  __syncthreads();
  const int o = threadIdx.x >> 1, kb = (threadIdx.x & 1) * 32;
  const int sw = (o & 15) << 3;
  unsigned* hip = wt + r * 8192;
  unsigned* lop = hip + 4096;
  for (int k = kb; k < kb + 32; k += 2) {
    float f0 = wl[k * 128 + o], f1 = wl[(k + 1) * 128 + o];
    unsigned h = cvt_pk_bf16(f0, f1);
    float l0 = f0 - __uint_as_float(h << 16);
    float l1 = f1 - __uint_as_float(h & 0xffff0000u);
    unsigned l = cvt_pk_bf16(l0, l1);
    int byte = o * 128 + ((k * 2) ^ sw);
    hip[byte >> 2] = h;
    lop[byte >> 2] = l;
  }
}

// ---------------------------------------------------------------------------
// K2: proj = sum_r pooled_r @ W_r via split-bf16 MFMA (hi*hi + hi*lo + lo*hi).
// B-operand read from TRANSPOSED pooled: 4 coalesced dword loads per frag
// (lane l31 = sample, consecutive addresses). 256 thr / 4 waves / 64 samp.
// ---------------------------------------------------------------------------
__global__ __launch_bounds__(256, 4) void rgc_mfma_kernel(
    const unsigned* __restrict__ wt, const unsigned* __restrict__ phi,
    const unsigned* __restrict__ plo, const int* __restrict__ nodes,
    const int* __restrict__ ord, float* __restrict__ out,
    int s0, int cnt, int cap)
{
  __shared__ short wl[2 * 8192];   // 32KB: W hi | lo tile for current r
  const int tid = threadIdx.x, lane = tid & 63, nt = tid >> 6;
  const int l31 = lane & 31, lhi = lane >> 5;
  const int sbase = blockIdx.x * 64;

  const int row = nt * 32 + l31;            // wT row = out index
  const int rsw = (row & 15) << 3;
  int aoff[8];
#pragma unroll
  for (int kc = 0; kc < 4; ++kc)
#pragma unroll
    for (int hf = 0; hf < 2; ++hf)
      aoff[kc * 2 + hf] = row * 64 + (((kc * 32 + lhi * 16 + hf * 8) ^ rsw) >> 1);

  f32x16 acc0 = {}, acc1 = {};

  for (int r = 0; r < NR; ++r) {
    __syncthreads();
    {
      const char* src = (const char*)(wt + r * 8192);
#pragma unroll
      for (int i = 0; i < 8; ++i) {
        int off = (i * 4 + nt) * 1024 + lane * 16;
        gload_lds16(src + off, (char*)wl + off);
      }
    }
    __syncthreads();

    bf16x8 ahi[4], alo[4];
#pragma unroll
    for (int kc = 0; kc < 4; ++kc) {
      U8 a, b;
      a.d[0] = *(const uint2*)&wl[aoff[kc * 2 + 0]];
      a.d[1] = *(const uint2*)&wl[aoff[kc * 2 + 1]];
      b.d[0] = *(const uint2*)&wl[8192 + aoff[kc * 2 + 0]];
      b.d[1] = *(const uint2*)&wl[8192 + aoff[kc * 2 + 1]];
      ahi[kc] = a.v; alo[kc] = b.v;
    }

#pragma unroll
    for (int st = 0; st < 2; ++st) {
      f32x16& accr = st ? acc1 : acc0;
      int scol = sbase + st * 32 + l31;
      size_t bb = (size_t)(r * 32 + lhi * 4) * cap + scol;
#pragma unroll
      for (int kc = 0; kc < 4; ++kc) {
        U8 bh, bl;
#pragma unroll
        for (int jp = 0; jp < 4; ++jp) {
          bh.u[jp] = phi[bb + (size_t)(kc * 8 + jp) * cap];
          bl.u[jp] = plo[bb + (size_t)(kc * 8 + jp) * cap];
        }
        accr = __builtin_amdgcn_mfma_f32_32x32x16_bf16(ahi[kc], bh.v, accr, 0, 0, 0);
        accr = __builtin_amdgcn_mfma_f32_32x32x16_bf16(ahi[kc], bl.v, accr, 0, 0, 0);
        accr = __builtin_amdgcn_mfma_f32_32x32x16_bf16(alo[kc], bh.v, accr, 0, 0, 0);
      }
    }
  }

#pragma unroll
  for (int st = 0; st < 2; ++st) {
    int sl = sbase + st * 32 + l31;
    if (sl < cnt) {
      int nd = nodes[ord[s0 + sl]];
      float* dst = out + (size_t)nd * OUTD + nt * 32;
      const f32x16& a = st ? acc1 : acc0;
#pragma unroll
      for (int j = 0; j < 16; ++j) {
        int m = (j & 3) + 8 * (j >> 2) + 4 * lhi;
        atomicAdd(dst + m, a[j]);
      }
    }
  }
}

__global__ void relu_kernel(float4* __restrict__ out, int n4) {
  int i = blockIdx.x * 256 + threadIdx.x;
  if (i < n4) {
    float4 v = out[i];
    v.x = fmaxf(v.x, 0.f); v.y = fmaxf(v.y, 0.f);
    v.z = fmaxf(v.z, 0.f); v.w = fmaxf(v.w, 0.f);
    out[i] = v;
  }
}

extern "C" void kernel_launch(void* const* d_in, const int* in_sizes, int n_in,
                              void* d_out, int out_size, void* d_ws, size_t ws_size,
                              hipStream_t stream) {
  const int*   nbr   = (const int*)d_in[0];
  const int*   lens  = (const int*)d_in[1];
  const int*   rels  = (const int*)d_in[2];
  const int*   nodes = (const int*)d_in[3];
  const float* adjw  = (const float*)d_in[4];
  const float* feat  = (const float*)d_in[5];
  const float* Wih   = (const float*)d_in[6];
  const float* Whh   = (const float*)d_in[7];
  const float* Wr    = (const float*)d_in[8];
  float* out = (float*)d_out;

  hipMemsetAsync(d_out, 0, (size_t)NS * OUTD * sizeof(float), stream);

  // ws layout: wt [0,360448) | fb bf16 feat [360448, 6760448) |
  //            ord [6760448, 6960448) | cnt/cur [6960448, +256) | phi/plo
  unsigned* wt  = (unsigned*)d_ws;
  unsigned* fb  = (unsigned*)((char*)d_ws + 360448);
  int*      ord = (int*)((char*)d_ws + 6760448);
  int*      cnt = (int*)((char*)d_ws + 6960448);
  int*      cur = cnt + 32;
  const size_t PHI_OFF = 6960768;
  unsigned* phi = (unsigned*)((char*)d_ws + PHI_OFF);

  wprep_kernel<<<NR, 256, 0, stream>>>(Wr, wt);
  fprep_kernel<<<(NS * IND / 2 + 255) / 256, 256, 0, stream>>>(feat, fb);
  zero_cnt_kernel<<<1, 64, 0, stream>>>(cnt);
  hist_kernel<<<(NS + 255) / 256, 256, 0, stream>>>(lens, cnt);
  prefix_kernel<<<1, 64, 0, stream>>>(cnt, cur);
  scatter_kernel<<<(NS + 255) / 256, 256, 0, stream>>>(lens, cur, ord);

  size_t avail = (ws_size > PHI_OFF) ? ws_size - PHI_OFF : 0;
  long long cap = (long long)(avail / 2816);     // samples (1408B x 2 planes)
  if (cap > NS + 64) cap = NS + 64;              // no need for more
  long long ch = cap - 64;                        // 64-sample read slack
  ch &= ~63LL;
  if (ch > NS) ch = NS;
  if (ch < 64) ch = 64;
  unsigned* plo = phi + (size_t)cap * 352;       // 352 u32 = 1408B per sample

  for (int s0 = 0; s0 < NS; s0 += (int)ch) {
    int cnt_c = (NS - s0 < (int)ch) ? (NS - s0) : (int)ch;
    lstm_mfma_kernel<<<(cnt_c + 31) / 32, 512, 0, stream>>>(
        fb, nbr, lens, rels, adjw, Wih, Whh, ord, phi, plo, s0, cnt_c, (int)cap);
    rgc_mfma_kernel<<<(cnt_c + 63) / 64, 256, 0, stream>>>(
        wt, phi, plo, nodes, ord, out, s0, cnt_c, (int)cap);
  }
  relu_kernel<<<(NS * OUTD / 4 + 255) / 256, 256, 0, stream>>>(
      (float4*)out, NS * OUTD / 4);
}

// Round 8
// 639.342 us; speedup vs baseline: 1.9454x; 1.6369x over previous
//
#include <hip/hip_runtime.h>

#define NS   50000
#define LSEQ 32
#define IND  64
#define HIDN 64
#define OUTD 128
#define NR   11

using bf16x8  = __attribute__((ext_vector_type(8))) short;
using f32x16  = __attribute__((ext_vector_type(16))) float;

union U8 { bf16x8 v; unsigned u[4]; uint2 d[2]; };

__device__ __forceinline__ unsigned cvt_pk_bf16(float a, float b) {
  unsigned r;
  asm volatile("v_cvt_pk_bf16_f32 %0, %1, %2" : "=v"(r) : "v"(a), "v"(b));
  return r;  // r[15:0] = bf16(a), r[31:16] = bf16(b)
}
__device__ __forceinline__ float fsig(float x) {
  return __builtin_amdgcn_rcpf(1.f + __expf(-x));
}
__device__ __forceinline__ float ftanh_(float x) {
  return 1.f - 2.f * __builtin_amdgcn_rcpf(__expf(2.f * x) + 1.f);
}
__device__ __forceinline__ void gload_lds16(const void* g, void* l) {
  __builtin_amdgcn_global_load_lds(
      (const __attribute__((address_space(1))) unsigned*)g,
      (__attribute__((address_space(3))) unsigned*)l, 16, 0, 0);
}

// ---------------- feature table -> bf16 (halves gather traffic) ------------
__global__ __launch_bounds__(256) void fprep_kernel(
    const float* __restrict__ f, unsigned* __restrict__ fb) {
  int i = blockIdx.x * 256 + threadIdx.x;      // uint index (2 floats)
  if (i < NS * IND / 2) {
    float2 v = ((const float2*)f)[i];
    fb[i] = cvt_pk_bf16(v.x, v.y);
  }
}

// ---------------- length sort (descending), LDS-binned ---------------------
__global__ void zero_cnt_kernel(int* cnt) {
  if (threadIdx.x < 64) cnt[threadIdx.x] = 0;  // cnt[32] + cur[32]
}
__global__ __launch_bounds__(256) void hist_kernel(
    const int* __restrict__ lens, int* __restrict__ cnt) {
  __shared__ int lc[32];
  int t = threadIdx.x;
  if (t < 32) lc[t] = 0;
  __syncthreads();
  int s = blockIdx.x * 256 + t;
  if (s < NS) atomicAdd(&lc[32 - lens[s]], 1);
  __syncthreads();
  if (t < 32 && lc[t]) atomicAdd(&cnt[t], lc[t]);
}
__global__ void prefix_kernel(const int* __restrict__ cnt, int* __restrict__ cur) {
  if (threadIdx.x == 0) {
    int sum = 0;
    for (int b = 0; b < 32; ++b) { cur[b] = sum; sum += cnt[b]; }
  }
}
__global__ __launch_bounds__(256) void scatter_kernel(
    const int* __restrict__ lens, int* __restrict__ cur, int* __restrict__ ord) {
  __shared__ int lc[32], lb[32];
  int t = threadIdx.x;
  if (t < 32) lc[t] = 0;
  __syncthreads();
  int s = blockIdx.x * 256 + t;
  int rank = 0, bin = 0;
  if (s < NS) {
    bin = 32 - lens[s];
    rank = atomicAdd(&lc[bin], 1);      // LDS atomic (fast)
  }
  __syncthreads();
  if (t < 32 && lc[t]) lb[t] = atomicAdd(&cur[t], lc[t]);  // 32/block global
  __syncthreads();
  if (s < NS) ord[lb[bin] + rank] = s;
}

// ---------------------------------------------------------------------------
// K1: fused gather + bf16-MFMA LSTM + relation pooling, length-sorted blocks.
// 512 thr / 8 waves / 32 samples. (512,4): natural VGPR=64, NO SPILL (spill
// regression proven at min-waves 6 and 8 in R6/R7). Pooled output written
// TRANSPOSED: phi_T[r*32+u_pair][sample] (coalesced K1 write AND K2 read).
// ---------------------------------------------------------------------------
__global__ __launch_bounds__(512, 4) void lstm_mfma_kernel(
    const unsigned* __restrict__ fb, const int* __restrict__ nbr,
    const int* __restrict__ lens, const int* __restrict__ rels,
    const float* __restrict__ adjw, const float* __restrict__ Wih,
    const float* __restrict__ Whh, const int* __restrict__ ord,
    unsigned* __restrict__ phi, unsigned* __restrict__ plo,
    int s0, int cnt, int cap)
{
  __shared__ short xh[2 * 32 * 128];   // 16KB: 2 x [32 samp][128 k] bf16, swizzled
  __shared__ float sh_w[32][33];
  __shared__ int   sh_meta[32][33];    // rel<<16 | nbr (nbr < 2^16)
  __shared__ int   sh_len[32];

  const int tid   = threadIdx.x;
  const int lane  = tid & 63;
  const int w     = tid >> 6;
  const int sbase = blockIdx.x * 32;

  for (int i = tid; i < 32 * 32; i += 512) {
    int ss = i >> 5, l = i & 31;
    int gp = sbase + ss;
    bool ok = gp < cnt;
    int gs = ok ? ord[s0 + gp] : 0;
    size_t off = (size_t)gs * LSEQ + l;
    sh_w[ss][l]    = ok ? adjw[off] : 0.f;
    sh_meta[ss][l] = ok ? ((rels[off] << 16) | nbr[off]) : 0;
  }
  if (tid < 32) {
    int gp = sbase + tid;
    sh_len[tid] = (gp < cnt) ? lens[ord[s0 + gp]] : 0;
  }
  for (int i = tid; i < 2 * 32 * 128; i += 512) xh[i] = 0;

  // stationary A fragments (gate-permuted weight rows, bf16)
  bf16x8 Af[8];
  {
    const int rr = lane & 31, kh = lane >> 5;
    const int g = rr & 3, q = rr >> 2;
    const int u = w * 8 + 4 * (q & 1) + (q >> 1);
    const int row = g * 64 + u;
#pragma unroll
    for (int kc = 0; kc < 8; ++kc) {
      int k0 = kc * 16 + kh * 8;
      const float* src = (k0 < 64) ? (Wih + row * 64 + k0)
                                   : (Whh + row * 64 + (k0 - 64));
      float4 f0 = *(const float4*)(src);
      float4 f1 = *(const float4*)(src + 4);
      U8 a;
      a.u[0] = cvt_pk_bf16(f0.x, f0.y); a.u[1] = cvt_pk_bf16(f0.z, f0.w);
      a.u[2] = cvt_pk_bf16(f1.x, f1.y); a.u[3] = cvt_pk_bf16(f1.z, f1.w);
      Af[kc] = a.v;
    }
  }

  const int s    = lane & 31;          // gate-phase sample
  const int hi   = lane >> 5;
  const int sxor = (s & 15) << 4;
  const int u0   = w * 8 + 4 * hi;     // 4 consecutive units
  const int hoff = s * 128 + (((128 + u0 * 2) ^ sxor) >> 1);   // short idx
  const int gsamp = tid >> 4, gseg = tid & 15;                 // gather role
  const int goff  = gsamp * 128 + (((gseg * 8) ^ ((gsamp & 15) << 4)) >> 1);

  float c4[4] = {0.f, 0.f, 0.f, 0.f};
  float pooled[4][NR] = {};

  __syncthreads();
  const int len_s = sh_len[s];
  const int len_g = sh_len[gsamp];
  const int tmax  = (sh_len[0] + 1) & ~1;   // block max (descending sort), even

  {  // prologue: x_0 -> buf0 (bf16 row, uint2 per lane)
    uint2 xv = make_uint2(0u, 0u);
    if (0 < len_g) {
      int nid = sh_meta[gsamp][0] & 0xffff;
      xv = *(const uint2*)(fb + (size_t)nid * 32 + gseg * 2);
    }
    *(uint2*)&xh[goff] = xv;
  }
  uint2 xA = make_uint2(0u, 0u), xB;
  if (1 < len_g) {
    int nid = sh_meta[gsamp][1] & 0xffff;
    xA = *(const uint2*)(fb + (size_t)nid * 32 + gseg * 2);
  }
  __syncthreads();

#define HALFSTEP(bufR, bufW, XLOAD, XWRITE, tc)                              \
  {                                                                          \
    uint2 xn = make_uint2(0u, 0u);                                           \
    if ((tc) + 2 < len_g) {                                                  \
      int nid = sh_meta[gsamp][(tc) + 2] & 0xffff;                           \
      xn = *(const uint2*)(fb + (size_t)nid * 32 + gseg * 2);                \
    }                                                                        \
    XLOAD = xn;                                                              \
    f32x16 acc = {};                                                         \
    _Pragma("unroll")                                                        \
    for (int kc = 0; kc < 8; ++kc) {                                         \
      int roff = s * 128 + (((kc * 32 + hi * 16) ^ sxor) >> 1);              \
      bf16x8 b = *(const bf16x8*)(&xh[(bufR) + roff]);                       \
      acc = __builtin_amdgcn_mfma_f32_32x32x16_bf16(Af[kc], b, acc, 0, 0, 0);\
    }                                                                        \
    int pk = sh_meta[s][tc];                                                 \
    float wv = ((tc) < len_s) ? sh_w[s][tc] : 0.f;                           \
    int rl = pk >> 16;                                                       \
    float h4[4];                                                             \
    _Pragma("unroll")                                                        \
    for (int p = 0; p < 4; ++p) {                                            \
      float gi = fsig(acc[4 * p + 0]);                                       \
      float gf = fsig(acc[4 * p + 1]);                                       \
      float gg = ftanh_(acc[4 * p + 2]);                                     \
      float go = fsig(acc[4 * p + 3]);                                       \
      float cc = gf * c4[p] + gi * gg;                                       \
      c4[p] = cc;                                                            \
      h4[p] = go * ftanh_(cc);                                               \
    }                                                                        \
    _Pragma("unroll")                                                        \
    for (int r = 0; r < NR; ++r) {                                           \
      float mr = (rl == r) ? wv : 0.f;                                       \
      pooled[0][r] += mr * h4[0]; pooled[1][r] += mr * h4[1];                \
      pooled[2][r] += mr * h4[2]; pooled[3][r] += mr * h4[3];                \
    }                                                                        \
    *(uint2*)&xh[(bufW) + hoff] = make_uint2(cvt_pk_bf16(h4[0], h4[1]),      \
                                             cvt_pk_bf16(h4[2], h4[3]));     \
    *(uint2*)&xh[(bufW) + goff] = XWRITE;                                    \
    __syncthreads();                                                         \
  }

#pragma unroll 1
  for (int t = 0; t < tmax; t += 2) {
    HALFSTEP(0,    4096, xB, xA, t)
    HALFSTEP(4096, 0,    xA, xB, t + 1)
  }
#undef HALFSTEP

  // pooled -> TRANSPOSED hi/lo bf16 planes: phi[r*32 + u/2][sample]
  if (sbase + s < cnt) {
    int gpos = sbase + s;
    int up0 = (u0 >> 1);                       // = w*4 + 2*hi
#pragma unroll
    for (int r = 0; r < NR; ++r) {
      float p0 = pooled[0][r], p1 = pooled[1][r];
      float p2 = pooled[2][r], p3 = pooled[3][r];
      unsigned h0 = cvt_pk_bf16(p0, p1), h1 = cvt_pk_bf16(p2, p3);
      float l0 = p0 - __uint_as_float(h0 << 16);
      float l1 = p1 - __uint_as_float(h0 & 0xffff0000u);
      float l2 = p2 - __uint_as_float(h1 << 16);
      float l3 = p3 - __uint_as_float(h1 & 0xffff0000u);
      unsigned g0 = cvt_pk_bf16(l0, l1), g1 = cvt_pk_bf16(l2, l3);
      phi[(size_t)(r * 32 + up0) * cap + gpos]     = h0;
      phi[(size_t)(r * 32 + up0 + 1) * cap + gpos] = h1;
      plo[(size_t)(r * 32 + up0) * cap + gpos]     = g0;
      plo[(size_t)(r * 32 + up0 + 1) * cap + gpos] = g1;
    }
  }
}

// ---------------------------------------------------------------------------
// Prep: Wr[11][64][128] f32 -> wt[r]: [hi 16KB | lo 16KB], each [128 o][64 k]
// bf16 with baked 4-bit XOR swizzle (byte ^= (o&15)<<3) for conflict-free b64.
// ---------------------------------------------------------------------------
__global__ __launch_bounds__(256) void wprep_kernel(
    const float* __restrict__ Wr, unsigned* __restrict__ wt)
{
  __shared__ float wl[64 * 128];
  const int r = blockIdx.x;
  for (int i = threadIdx.x; i < 64 * 128; i += 256)
    wl[i] = Wr[r * 64 * 128 + i];
  __syncthreads();
  const int o = threadIdx.x >> 1, kb = (threadIdx.x & 1) * 32;
  const int sw = (o & 15) << 3;
  unsigned* hip = wt + r * 8192;
  unsigned* lop = hip + 4096;
  for (int k = kb; k < kb + 32; k += 2) {
    float f0 = wl[k * 128 + o], f1 = wl[(k + 1) * 128 + o];
    unsigned h = cvt_pk_bf16(f0, f1);
    float l0 = f0 - __uint_as_float(h << 16);
    float l1 = f1 - __uint_as_float(h & 0xffff0000u);
    unsigned l = cvt_pk_bf16(l0, l1);
    int byte = o * 128 + ((k * 2) ^ sw);
    hip[byte >> 2] = h;
    lop[byte >> 2] = l;
  }
}

// ---------------------------------------------------------------------------
// K2: proj = sum_r pooled_r @ W_r via split-bf16 MFMA (hi*hi + hi*lo + lo*hi).
// B-operand read from TRANSPOSED pooled: 4 coalesced dword loads per frag
// (lane l31 = sample, consecutive addresses). 256 thr / 4 waves / 64 samp.
// ---------------------------------------------------------------------------
__global__ __launch_bounds__(256, 4) void rgc_mfma_kernel(
    const unsigned* __restrict__ wt, const unsigned* __restrict__ phi,
    const unsigned* __restrict__ plo, const int* __restrict__ nodes,
    const int* __restrict__ ord, float* __restrict__ out,
    int s0, int cnt, int cap)
{
  __shared__ short wl[2 * 8192];   // 32KB: W hi | lo tile for current r
  const int tid = threadIdx.x, lane = tid & 63, nt = tid >> 6;
  const int l31 = lane & 31, lhi = lane >> 5;
  const int sbase = blockIdx.x * 64;

  const int row = nt * 32 + l31;            // wT row = out index
  const int rsw = (row & 15) << 3;
  int aoff[8];
#pragma unroll
  for (int kc = 0; kc < 4; ++kc)
#pragma unroll
    for (int hf = 0; hf < 2; ++hf)
      aoff[kc * 2 + hf] = row * 64 + (((kc * 32 + lhi * 16 + hf * 8) ^ rsw) >> 1);

  f32x16 acc0 = {}, acc1 = {};

  for (int r = 0; r < NR; ++r) {
    __syncthreads();
    {
      const char* src = (const char*)(wt + r * 8192);
#pragma unroll
      for (int i = 0; i < 8; ++i) {
        int off = (i * 4 + nt) * 1024 + lane * 16;
        gload_lds16(src + off, (char*)wl + off);
      }
    }
    __syncthreads();

    bf16x8 ahi[4], alo[4];
#pragma unroll
    for (int kc = 0; kc < 4; ++kc) {
      U8 a, b;
      a.d[0] = *(const uint2*)&wl[aoff[kc * 2 + 0]];
      a.d[1] = *(const uint2*)&wl[aoff[kc * 2 + 1]];
      b.d[0] = *(const uint2*)&wl[8192 + aoff[kc * 2 + 0]];
      b.d[1] = *(const uint2*)&wl[8192 + aoff[kc * 2 + 1]];
      ahi[kc] = a.v; alo[kc] = b.v;
    }

#pragma unroll
    for (int st = 0; st < 2; ++st) {
      f32x16& accr = st ? acc1 : acc0;
      int scol = sbase + st * 32 + l31;
      size_t bb = (size_t)(r * 32 + lhi * 4) * cap + scol;
#pragma unroll
      for (int kc = 0; kc < 4; ++kc) {
        U8 bh, bl;
#pragma unroll
        for (int jp = 0; jp < 4; ++jp) {
          bh.u[jp] = phi[bb + (size_t)(kc * 8 + jp) * cap];
          bl.u[jp] = plo[bb + (size_t)(kc * 8 + jp) * cap];
        }
        accr = __builtin_amdgcn_mfma_f32_32x32x16_bf16(ahi[kc], bh.v, accr, 0, 0, 0);
        accr = __builtin_amdgcn_mfma_f32_32x32x16_bf16(ahi[kc], bl.v, accr, 0, 0, 0);
        accr = __builtin_amdgcn_mfma_f32_32x32x16_bf16(alo[kc], bh.v, accr, 0, 0, 0);
      }
    }
  }

#pragma unroll
  for (int st = 0; st < 2; ++st) {
    int sl = sbase + st * 32 + l31;
    if (sl < cnt) {
      int nd = nodes[ord[s0 + sl]];
      float* dst = out + (size_t)nd * OUTD + nt * 32;
      const f32x16& a = st ? acc1 : acc0;
#pragma unroll
      for (int j = 0; j < 16; ++j) {
        int m = (j & 3) + 8 * (j >> 2) + 4 * lhi;
        atomicAdd(dst + m, a[j]);
      }
    }
  }
}

__global__ void relu_kernel(float4* __restrict__ out, int n4) {
  int i = blockIdx.x * 256 + threadIdx.x;
  if (i < n4) {
    float4 v = out[i];
    v.x = fmaxf(v.x, 0.f); v.y = fmaxf(v.y, 0.f);
    v.z = fmaxf(v.z, 0.f); v.w = fmaxf(v.w, 0.f);
    out[i] = v;
  }
}

extern "C" void kernel_launch(void* const* d_in, const int* in_sizes, int n_in,
                              void* d_out, int out_size, void* d_ws, size_t ws_size,
                              hipStream_t stream) {
  const int*   nbr   = (const int*)d_in[0];
  const int*   lens  = (const int*)d_in[1];
  const int*   rels  = (const int*)d_in[2];
  const int*   nodes = (const int*)d_in[3];
  const float* adjw  = (const float*)d_in[4];
  const float* feat  = (const float*)d_in[5];
  const float* Wih   = (const float*)d_in[6];
  const float* Whh   = (const float*)d_in[7];
  const float* Wr    = (const float*)d_in[8];
  float* out = (float*)d_out;

  hipMemsetAsync(d_out, 0, (size_t)NS * OUTD * sizeof(float), stream);

  // ws layout: wt [0,360448) | fb bf16 feat [360448, 6760448) |
  //            ord [6760448, 6960448) | cnt/cur [6960448, +256) | phi/plo
  unsigned* wt  = (unsigned*)d_ws;
  unsigned* fb  = (unsigned*)((char*)d_ws + 360448);
  int*      ord = (int*)((char*)d_ws + 6760448);
  int*      cnt = (int*)((char*)d_ws + 6960448);
  int*      cur = cnt + 32;
  const size_t PHI_OFF = 6960768;
  unsigned* phi = (unsigned*)((char*)d_ws + PHI_OFF);

  wprep_kernel<<<NR, 256, 0, stream>>>(Wr, wt);
  fprep_kernel<<<(NS * IND / 2 + 255) / 256, 256, 0, stream>>>(feat, fb);
  zero_cnt_kernel<<<1, 64, 0, stream>>>(cnt);
  hist_kernel<<<(NS + 255) / 256, 256, 0, stream>>>(lens, cnt);
  prefix_kernel<<<1, 64, 0, stream>>>(cnt, cur);
  scatter_kernel<<<(NS + 255) / 256, 256, 0, stream>>>(lens, cur, ord);

  size_t avail = (ws_size > PHI_OFF) ? ws_size - PHI_OFF : 0;
  long long cap = (long long)(avail / 2816);     // samples (1408B x 2 planes)
  if (cap > NS + 64) cap = NS + 64;              // no need for more
  long long ch = cap - 64;                        // 64-sample read slack
  ch &= ~63LL;
  if (ch > NS) ch = NS;
  if (ch < 64) ch = 64;
  unsigned* plo = phi + (size_t)cap * 352;       // 352 u32 = 1408B per sample

  for (int s0 = 0; s0 < NS; s0 += (int)ch) {
    int cnt_c = (NS - s0 < (int)ch) ? (NS - s0) : (int)ch;
    lstm_mfma_kernel<<<(cnt_c + 31) / 32, 512, 0, stream>>>(
        fb, nbr, lens, rels, adjw, Wih, Whh, ord, phi, plo, s0, cnt_c, (int)cap);
    rgc_mfma_kernel<<<(cnt_c + 63) / 64, 256, 0, stream>>>(
        wt, phi, plo, nodes, ord, out, s0, cnt_c, (int)cap);
  }
  relu_kernel<<<(NS * OUTD / 4 + 255) / 256, 256, 0, stream>>>(
      (float4*)out, NS * OUTD / 4);
}

// Round 10
// 488.150 us; speedup vs baseline: 2.5479x; 1.3097x over previous
//
#include <hip/hip_runtime.h>

#define NS   50000
#define LSEQ 32
#define IND  64
#define HIDN 64
#define OUTD 128
#define NR   11

using bf16x8  = __attribute__((ext_vector_type(8))) short;
using f32x16  = __attribute__((ext_vector_type(16))) float;

union U8 { bf16x8 v; unsigned u[4]; uint2 d[2]; };

__device__ __forceinline__ unsigned cvt_pk_bf16(float a, float b) {
  unsigned r;
  asm volatile("v_cvt_pk_bf16_f32 %0, %1, %2" : "=v"(r) : "v"(a), "v"(b));
  return r;  // r[15:0] = bf16(a), r[31:16] = bf16(b)
}
__device__ __forceinline__ float fsig(float x) {
  return __builtin_amdgcn_rcpf(1.f + __expf(-x));
}
__device__ __forceinline__ float ftanh_(float x) {
  return 1.f - 2.f * __builtin_amdgcn_rcpf(__expf(2.f * x) + 1.f);
}

// ---------------- feature table -> bf16 (halves gather traffic) ------------
__global__ __launch_bounds__(256) void fprep_kernel(
    const float* __restrict__ f, unsigned* __restrict__ fb) {
  int i = blockIdx.x * 256 + threadIdx.x;      // uint index (2 floats)
  if (i < NS * IND / 2) {
    float2 v = ((const float2*)f)[i];
    fb[i] = cvt_pk_bf16(v.x, v.y);
  }
}

// ---------------- length sort (descending), LDS-binned ---------------------
__global__ void zero_cnt_kernel(int* cnt) {
  if (threadIdx.x < 64) cnt[threadIdx.x] = 0;  // cnt[32] + cur[32]
}
__global__ __launch_bounds__(256) void hist_kernel(
    const int* __restrict__ lens, int* __restrict__ cnt) {
  __shared__ int lc[32];
  int t = threadIdx.x;
  if (t < 32) lc[t] = 0;
  __syncthreads();
  int s = blockIdx.x * 256 + t;
  if (s < NS) atomicAdd(&lc[32 - lens[s]], 1);
  __syncthreads();
  if (t < 32 && lc[t]) atomicAdd(&cnt[t], lc[t]);
}
__global__ void prefix_kernel(const int* __restrict__ cnt, int* __restrict__ cur) {
  if (threadIdx.x == 0) {
    int sum = 0;
    for (int b = 0; b < 32; ++b) { cur[b] = sum; sum += cnt[b]; }
  }
}
__global__ __launch_bounds__(256) void scatter_kernel(
    const int* __restrict__ lens, int* __restrict__ cur, int* __restrict__ ord) {
  __shared__ int lc[32], lb[32];
  int t = threadIdx.x;
  if (t < 32) lc[t] = 0;
  __syncthreads();
  int s = blockIdx.x * 256 + t;
  int rank = 0, bin = 0;
  if (s < NS) {
    bin = 32 - lens[s];
    rank = atomicAdd(&lc[bin], 1);      // LDS atomic (fast)
  }
  __syncthreads();
  if (t < 32 && lc[t]) lb[t] = atomicAdd(&cur[t], lc[t]);  // 32/block global
  __syncthreads();
  if (s < NS) ord[lb[bin] + rank] = s;
}

// ---------------------------------------------------------------------------
// Prep: Wr[11][64][128] f32 -> wt2: per-lane-major A fragments for the fused
// projection. frag_idx = ((r*4+nt)*4+kc)*2+pl; u32 offset = frag_idx*256 +
// lane*4; each 16B = W^T(pl)[row=nt*32+(lane&31)][k0..k0+7], k0=kc*16+(lane>>5)*8.
// ---------------------------------------------------------------------------
__global__ __launch_bounds__(256) void wprep_kernel(
    const float* __restrict__ Wr, unsigned* __restrict__ wt2)
{
  __shared__ float wl[64 * 128];
  const int r = blockIdx.x;
  for (int i = threadIdx.x; i < 64 * 128; i += 256)
    wl[i] = Wr[r * 64 * 128 + i];
  __syncthreads();
  for (int idx = threadIdx.x; idx < 2048; idx += 256) {
    int lane = idx & 63;
    int pl   = (idx >> 6) & 1;
    int kc   = (idx >> 7) & 3;
    int nt   = (idx >> 9) & 3;
    int row  = nt * 32 + (lane & 31);          // out index o
    int k0   = kc * 16 + (lane >> 5) * 8;      // hidden-unit k
    unsigned o4[4];
#pragma unroll
    for (int jp = 0; jp < 4; ++jp) {
      float a = wl[(k0 + jp * 2) * 128 + row];      // W[k][o]
      float b = wl[(k0 + jp * 2 + 1) * 128 + row];
      unsigned h = cvt_pk_bf16(a, b);
      if (pl) {
        float la = a - __uint_as_float(h << 16);
        float lb = b - __uint_as_float(h & 0xffff0000u);
        h = cvt_pk_bf16(la, lb);
      }
      o4[jp] = h;
    }
    size_t dst = (size_t)(((r * 4 + nt) * 4 + kc) * 2 + pl) * 256 + lane * 4;
    *(uint4*)(wt2 + dst) = *(uint4*)o4;
  }
}

// ---------------------------------------------------------------------------
// K1: FULLY FUSED gather + bf16-MFMA LSTM + relation pooling + projection +
// atomic scatter. 512 thr / 8 waves / 32 samples, length-sorted blocks,
// (512,4). Epilogue exchange goes through a DEDICATED LINEAR LDS buffer pb
// (no swizzle; A/B vs R9's swizzled xh reuse) and uses the FULL 4-term
// split-bf16 product (hi*hi + hi*lo + lo*hi + lo*lo) for fp32-grade accuracy.
// ---------------------------------------------------------------------------
__global__ __launch_bounds__(512, 4) void lstm_mfma_kernel(
    const unsigned* __restrict__ fb, const int* __restrict__ nbr,
    const int* __restrict__ lens, const int* __restrict__ rels,
    const float* __restrict__ adjw, const float* __restrict__ Wih,
    const float* __restrict__ Whh, const int* __restrict__ ord,
    const int* __restrict__ nodes, const unsigned* __restrict__ wt2,
    float* __restrict__ out, int s0, int cnt)
{
  __shared__ __align__(16) short xh[2 * 32 * 128]; // 16KB, 2 x [32 s][256B], swizzled
  __shared__ __align__(16) short pb[32 * 136];     // 8.5KB: [32 s][64 hi|64 lo|8 pad]
  __shared__ float sh_w[32][33];
  __shared__ int   sh_meta[32][33];    // rel<<16 | nbr (nbr < 2^16)
  __shared__ int   sh_len[32];
  __shared__ int   sh_nodes[32];

  const int tid   = threadIdx.x;
  const int lane  = tid & 63;
  const int w     = tid >> 6;
  const int sbase = blockIdx.x * 32;

  for (int i = tid; i < 32 * 32; i += 512) {
    int ss = i >> 5, l = i & 31;
    int gp = sbase + ss;
    bool ok = gp < cnt;
    int gs = ok ? ord[s0 + gp] : 0;
    size_t off = (size_t)gs * LSEQ + l;
    sh_w[ss][l]    = ok ? adjw[off] : 0.f;
    sh_meta[ss][l] = ok ? ((rels[off] << 16) | nbr[off]) : 0;
  }
  if (tid < 32) {
    int gp = sbase + tid;
    bool ok = gp < cnt;
    int gs = ok ? ord[s0 + gp] : 0;
    sh_len[tid]   = ok ? lens[gs] : 0;
    sh_nodes[tid] = ok ? nodes[gs] : 0;
  }
  for (int i = tid; i < 2 * 32 * 128; i += 512) xh[i] = 0;

  // stationary A fragments (gate-permuted weight rows, bf16)
  bf16x8 Af[8];
  {
    const int rr = lane & 31, kh = lane >> 5;
    const int g = rr & 3, q = rr >> 2;
    const int u = w * 8 + 4 * (q & 1) + (q >> 1);
    const int row = g * 64 + u;
#pragma unroll
    for (int kc = 0; kc < 8; ++kc) {
      int k0 = kc * 16 + kh * 8;
      const float* src = (k0 < 64) ? (Wih + row * 64 + k0)
                                   : (Whh + row * 64 + (k0 - 64));
      float4 f0 = *(const float4*)(src);
      float4 f1 = *(const float4*)(src + 4);
      U8 a;
      a.u[0] = cvt_pk_bf16(f0.x, f0.y); a.u[1] = cvt_pk_bf16(f0.z, f0.w);
      a.u[2] = cvt_pk_bf16(f1.x, f1.y); a.u[3] = cvt_pk_bf16(f1.z, f1.w);
      Af[kc] = a.v;
    }
  }

  const int s    = lane & 31;          // gate-phase / B-col sample
  const int hi   = lane >> 5;
  const int sxor = (s & 15) << 4;
  const int u0   = w * 8 + 4 * hi;     // 4 consecutive units
  const int hoff = s * 128 + (((128 + u0 * 2) ^ sxor) >> 1);   // short idx
  const int gsamp = tid >> 4, gseg = tid & 15;                 // gather role
  const int goff  = gsamp * 128 + (((gseg * 8) ^ ((gsamp & 15) << 4)) >> 1);

  float c4[4] = {0.f, 0.f, 0.f, 0.f};
  float pooled[4][NR] = {};

  __syncthreads();
  const int len_s = sh_len[s];
  const int len_g = sh_len[gsamp];
  const int tmax  = (sh_len[0] + 1) & ~1;   // block max (descending sort), even

  {  // prologue: x_0 -> buf0 (bf16 row, uint2 per lane)
    uint2 xv = make_uint2(0u, 0u);
    if (0 < len_g) {
      int nid = sh_meta[gsamp][0] & 0xffff;
      xv = *(const uint2*)(fb + (size_t)nid * 32 + gseg * 2);
    }
    *(uint2*)&xh[goff] = xv;
  }
  uint2 xA = make_uint2(0u, 0u), xB;
  if (1 < len_g) {
    int nid = sh_meta[gsamp][1] & 0xffff;
    xA = *(const uint2*)(fb + (size_t)nid * 32 + gseg * 2);
  }
  __syncthreads();

#define HALFSTEP(bufR, bufW, XLOAD, XWRITE, tc)                              \
  {                                                                          \
    uint2 xn = make_uint2(0u, 0u);                                           \
    if ((tc) + 2 < len_g) {                                                  \
      int nid = sh_meta[gsamp][(tc) + 2] & 0xffff;                           \
      xn = *(const uint2*)(fb + (size_t)nid * 32 + gseg * 2);                \
    }                                                                        \
    XLOAD = xn;                                                              \
    f32x16 acc = {};                                                         \
    _Pragma("unroll")                                                        \
    for (int kc = 0; kc < 8; ++kc) {                                         \
      int roff = s * 128 + (((kc * 32 + hi * 16) ^ sxor) >> 1);              \
      bf16x8 b = *(const bf16x8*)(&xh[(bufR) + roff]);                       \
      acc = __builtin_amdgcn_mfma_f32_32x32x16_bf16(Af[kc], b, acc, 0, 0, 0);\
    }                                                                        \
    int pk = sh_meta[s][tc];                                                 \
    float wv = ((tc) < len_s) ? sh_w[s][tc] : 0.f;                           \
    int rl = pk >> 16;                                                       \
    float h4[4];                                                             \
    _Pragma("unroll")                                                        \
    for (int p = 0; p < 4; ++p) {                                            \
      float gi = fsig(acc[4 * p + 0]);                                       \
      float gf = fsig(acc[4 * p + 1]);                                       \
      float gg = ftanh_(acc[4 * p + 2]);                                     \
      float go = fsig(acc[4 * p + 3]);                                       \
      float cc = gf * c4[p] + gi * gg;                                       \
      c4[p] = cc;                                                            \
      h4[p] = go * ftanh_(cc);                                               \
    }                                                                        \
    _Pragma("unroll")                                                        \
    for (int r = 0; r < NR; ++r) {                                           \
      float mr = (rl == r) ? wv : 0.f;                                       \
      pooled[0][r] += mr * h4[0]; pooled[1][r] += mr * h4[1];                \
      pooled[2][r] += mr * h4[2]; pooled[3][r] += mr * h4[3];                \
    }                                                                        \
    *(uint2*)&xh[(bufW) + hoff] = make_uint2(cvt_pk_bf16(h4[0], h4[1]),      \
                                             cvt_pk_bf16(h4[2], h4[3]));     \
    *(uint2*)&xh[(bufW) + goff] = XWRITE;                                    \
    __syncthreads();                                                         \
  }

#pragma unroll 1
  for (int t = 0; t < tmax; t += 2) {
    HALFSTEP(0,    4096, xB, xA, t)
    HALFSTEP(4096, 0,    xA, xB, t + 1)
  }
#undef HALFSTEP

  // ---- fused projection epilogue: proj = sum_r pooled_r @ W_r ----
  // pb row s: shorts [s*136 + u] = hi(unit u), [s*136 + 64 + u] = lo(unit u).
  f32x16 pacc = {};
  const bool mw = (w < 4);             // MFMA waves; wave w owns out rows w*32..+31
#pragma unroll
  for (int r = 0; r < NR; ++r) {
    {
      float p0 = pooled[0][r], p1 = pooled[1][r];
      float p2 = pooled[2][r], p3 = pooled[3][r];
      unsigned h0 = cvt_pk_bf16(p0, p1), h1 = cvt_pk_bf16(p2, p3);
      float l0 = p0 - __uint_as_float(h0 << 16);
      float l1 = p1 - __uint_as_float(h0 & 0xffff0000u);
      float l2 = p2 - __uint_as_float(h1 << 16);
      float l3 = p3 - __uint_as_float(h1 & 0xffff0000u);
      unsigned g0 = cvt_pk_bf16(l0, l1), g1 = cvt_pk_bf16(l2, l3);
      *(uint2*)&pb[s * 136 + u0]      = make_uint2(h0, h1);
      *(uint2*)&pb[s * 136 + 64 + u0] = make_uint2(g0, g1);
    }
    __syncthreads();
    if (mw) {
#pragma unroll
      for (int kc = 0; kc < 4; ++kc) {
        int fi = ((r * 4 + w) * 4 + kc) * 2;
        U8 ah, al;
        *(uint4*)ah.u = *(const uint4*)(wt2 + (size_t)fi * 256 + lane * 4);
        *(uint4*)al.u = *(const uint4*)(wt2 + (size_t)(fi + 1) * 256 + lane * 4);
        bf16x8 bh = *(const bf16x8*)(&pb[s * 136 + kc * 16 + hi * 8]);
        bf16x8 bl = *(const bf16x8*)(&pb[s * 136 + 64 + kc * 16 + hi * 8]);
        pacc = __builtin_amdgcn_mfma_f32_32x32x16_bf16(ah.v, bh, pacc, 0, 0, 0);
        pacc = __builtin_amdgcn_mfma_f32_32x32x16_bf16(ah.v, bl, pacc, 0, 0, 0);
        pacc = __builtin_amdgcn_mfma_f32_32x32x16_bf16(al.v, bh, pacc, 0, 0, 0);
        pacc = __builtin_amdgcn_mfma_f32_32x32x16_bf16(al.v, bl, pacc, 0, 0, 0);
      }
    }
    __syncthreads();
  }

  if (mw && (sbase + s) < cnt) {
    int nd = sh_nodes[s];
    float* dst = out + (size_t)nd * OUTD + w * 32;
#pragma unroll
    for (int j = 0; j < 16; ++j) {
      int m = (j & 3) + 8 * (j >> 2) + 4 * hi;
      atomicAdd(dst + m, pacc[j]);
    }
  }
}

__global__ void relu_kernel(float4* __restrict__ out, int n4) {
  int i = blockIdx.x * 256 + threadIdx.x;
  if (i < n4) {
    float4 v = out[i];
    v.x = fmaxf(v.x, 0.f); v.y = fmaxf(v.y, 0.f);
    v.z = fmaxf(v.z, 0.f); v.w = fmaxf(v.w, 0.f);
    out[i] = v;
  }
}

extern "C" void kernel_launch(void* const* d_in, const int* in_sizes, int n_in,
                              void* d_out, int out_size, void* d_ws, size_t ws_size,
                              hipStream_t stream) {
  const int*   nbr   = (const int*)d_in[0];
  const int*   lens  = (const int*)d_in[1];
  const int*   rels  = (const int*)d_in[2];
  const int*   nodes = (const int*)d_in[3];
  const float* adjw  = (const float*)d_in[4];
  const float* feat  = (const float*)d_in[5];
  const float* Wih   = (const float*)d_in[6];
  const float* Whh   = (const float*)d_in[7];
  const float* Wr    = (const float*)d_in[8];
  float* out = (float*)d_out;

  hipMemsetAsync(d_out, 0, (size_t)NS * OUTD * sizeof(float), stream);

  // ws layout: wt2 [0,360448) | fb bf16 feat [360448, 6760448) |
  //            ord [6760448, 6960448) | cnt/cur [6960448, +256)
  unsigned* wt2 = (unsigned*)d_ws;
  unsigned* fb  = (unsigned*)((char*)d_ws + 360448);
  int*      ord = (int*)((char*)d_ws + 6760448);
  int*      cnt = (int*)((char*)d_ws + 6960448);
  int*      cur = cnt + 32;

  wprep_kernel<<<NR, 256, 0, stream>>>(Wr, wt2);
  fprep_kernel<<<(NS * IND / 2 + 255) / 256, 256, 0, stream>>>(feat, fb);
  zero_cnt_kernel<<<1, 64, 0, stream>>>(cnt);
  hist_kernel<<<(NS + 255) / 256, 256, 0, stream>>>(lens, cnt);
  prefix_kernel<<<1, 64, 0, stream>>>(cnt, cur);
  scatter_kernel<<<(NS + 255) / 256, 256, 0, stream>>>(lens, cur, ord);

  lstm_mfma_kernel<<<(NS + 31) / 32, 512, 0, stream>>>(
      fb, nbr, lens, rels, adjw, Wih, Whh, ord, nodes, wt2, out, 0, NS);

  relu_kernel<<<(NS * OUTD / 4 + 255) / 256, 256, 0, stream>>>(
      (float4*)out, NS * OUTD / 4);
}

// Round 11
// 313.839 us; speedup vs baseline: 3.9631x; 1.5554x over previous
//
#include <hip/hip_runtime.h>

#define NS   50000
#define LSEQ 32
#define IND  64
#define HIDN 64
#define OUTD 128
#define NR   11

using bf16x8  = __attribute__((ext_vector_type(8))) short;
using f32x16  = __attribute__((ext_vector_type(16))) float;

union U8 { bf16x8 v; unsigned u[4]; uint2 d[2]; };

__device__ __forceinline__ unsigned cvt_pk_bf16(float a, float b) {
  unsigned r;
  asm volatile("v_cvt_pk_bf16_f32 %0, %1, %2" : "=v"(r) : "v"(a), "v"(b));
  return r;  // r[15:0] = bf16(a), r[31:16] = bf16(b)
}
__device__ __forceinline__ float fsig(float x) {
  return __builtin_amdgcn_rcpf(1.f + __expf(-x));
}
__device__ __forceinline__ float ftanh_(float x) {
  return 1.f - 2.f * __builtin_amdgcn_rcpf(__expf(2.f * x) + 1.f);
}

// ---------------- feature table -> bf16 (halves gather traffic) ------------
__global__ __launch_bounds__(256) void fprep_kernel(
    const float* __restrict__ f, unsigned* __restrict__ fb) {
  int i = blockIdx.x * 256 + threadIdx.x;      // uint index (2 floats)
  if (i < NS * IND / 2) {
    float2 v = ((const float2*)f)[i];
    fb[i] = cvt_pk_bf16(v.x, v.y);
  }
}

// ---------------- length sort (descending), LDS-binned ---------------------
__global__ void zero_cnt_kernel(int* cnt) {
  if (threadIdx.x < 64) cnt[threadIdx.x] = 0;  // cnt[32] + cur[32]
}
__global__ __launch_bounds__(256) void hist_kernel(
    const int* __restrict__ lens, int* __restrict__ cnt) {
  __shared__ int lc[32];
  int t = threadIdx.x;
  if (t < 32) lc[t] = 0;
  __syncthreads();
  int s = blockIdx.x * 256 + t;
  if (s < NS) atomicAdd(&lc[32 - lens[s]], 1);
  __syncthreads();
  if (t < 32 && lc[t]) atomicAdd(&cnt[t], lc[t]);
}
__global__ void prefix_kernel(const int* __restrict__ cnt, int* __restrict__ cur) {
  if (threadIdx.x == 0) {
    int sum = 0;
    for (int b = 0; b < 32; ++b) { cur[b] = sum; sum += cnt[b]; }
  }
}
__global__ __launch_bounds__(256) void scatter_kernel(
    const int* __restrict__ lens, int* __restrict__ cur, int* __restrict__ ord) {
  __shared__ int lc[32], lb[32];
  int t = threadIdx.x;
  if (t < 32) lc[t] = 0;
  __syncthreads();
  int s = blockIdx.x * 256 + t;
  int rank = 0, bin = 0;
  if (s < NS) {
    bin = 32 - lens[s];
    rank = atomicAdd(&lc[bin], 1);      // LDS atomic (fast)
  }
  __syncthreads();
  if (t < 32 && lc[t]) lb[t] = atomicAdd(&cur[t], lc[t]);  // 32/block global
  __syncthreads();
  if (s < NS) ord[lb[bin] + rank] = s;
}

// ---------------------------------------------------------------------------
// Prep: Wr[11][64][128] f32 -> wt2: per-lane-major A fragments for the fused
// projection. frag_idx = ((r*4+nt)*4+kc)*2+pl; u32 offset = frag_idx*256 +
// lane*4; each 16B = W^T(pl)[row=nt*32+(lane&31)][k0..k0+7], k0=kc*16+(lane>>5)*8.
// ---------------------------------------------------------------------------
__global__ __launch_bounds__(256) void wprep_kernel(
    const float* __restrict__ Wr, unsigned* __restrict__ wt2)
{
  __shared__ float wl[64 * 128];
  const int r = blockIdx.x;
  for (int i = threadIdx.x; i < 64 * 128; i += 256)
    wl[i] = Wr[r * 64 * 128 + i];
  __syncthreads();
  for (int idx = threadIdx.x; idx < 2048; idx += 256) {
    int lane = idx & 63;
    int pl   = (idx >> 6) & 1;
    int kc   = (idx >> 7) & 3;
    int nt   = (idx >> 9) & 3;
    int row  = nt * 32 + (lane & 31);          // out index o
    int k0   = kc * 16 + (lane >> 5) * 8;      // hidden-unit k
    unsigned o4[4];
#pragma unroll
    for (int jp = 0; jp < 4; ++jp) {
      float a = wl[(k0 + jp * 2) * 128 + row];      // W[k][o]
      float b = wl[(k0 + jp * 2 + 1) * 128 + row];
      unsigned h = cvt_pk_bf16(a, b);
      if (pl) {
        float la = a - __uint_as_float(h << 16);
        float lb = b - __uint_as_float(h & 0xffff0000u);
        h = cvt_pk_bf16(la, lb);
      }
      o4[jp] = h;
    }
    size_t dst = (size_t)(((r * 4 + nt) * 4 + kc) * 2 + pl) * 256 + lane * 4;
    *(uint4*)(wt2 + dst) = *(uint4*)o4;
  }
}

// ---------------------------------------------------------------------------
// K1: FULLY FUSED gather + bf16-MFMA LSTM + relation pooling + projection +
// atomic scatter. 512 thr / 8 waves / 32 samples, length-sorted blocks.
// x pre-staged 4 timesteps ahead into an 8-slot LDS ring via global_load_lds
// (linear dest + source-permuted swizzle), issued at phase t%4==3 so the
// barrier vmcnt-drain hides under that phase's compute; the other 3 phases
// carry no outstanding vmem -> their barrier drains are free.
// ---------------------------------------------------------------------------
__global__ __launch_bounds__(512, 4) void lstm_mfma_kernel(
    const unsigned* __restrict__ fb, const int* __restrict__ nbr,
    const int* __restrict__ lens, const int* __restrict__ rels,
    const float* __restrict__ adjw, const float* __restrict__ Wih,
    const float* __restrict__ Whh, const int* __restrict__ ord,
    const int* __restrict__ nodes, const unsigned* __restrict__ wt2,
    float* __restrict__ out, int s0, int cnt)
{
  __shared__ __align__(16) short xq[8 * 32 * 64];  // 32KB: 8 slots x [32 s][128B x]
  __shared__ __align__(16) short hb[2 * 32 * 64];  // 8KB: 2 bufs x [32 s][128B h]
  __shared__ float sh_w[32][33];
  __shared__ int   sh_meta[32][33];    // rel<<16 | nbr (nbr < 2^16)
  __shared__ int   sh_len[32];
  __shared__ int   sh_nodes[32];

  const int tid   = threadIdx.x;
  const int lane  = tid & 63;
  const int w     = tid >> 6;
  const int sbase = blockIdx.x * 32;

  for (int i = tid; i < 32 * 32; i += 512) {
    int ss = i >> 5, l = i & 31;
    int gp = sbase + ss;
    bool ok = gp < cnt;
    int gs = ok ? ord[s0 + gp] : 0;
    size_t off = (size_t)gs * LSEQ + l;
    sh_w[ss][l]    = ok ? adjw[off] : 0.f;
    sh_meta[ss][l] = ok ? ((rels[off] << 16) | nbr[off]) : 0;
  }
  if (tid < 32) {
    int gp = sbase + tid;
    bool ok = gp < cnt;
    int gs = ok ? ord[s0 + gp] : 0;
    sh_len[tid]   = ok ? lens[gs] : 0;
    sh_nodes[tid] = ok ? nodes[gs] : 0;
  }
  for (int i = tid; i < 2 * 32 * 64; i += 512) hb[i] = 0;   // h(0) = 0

  // stationary A fragments (gate-permuted weight rows, bf16)
  bf16x8 Af[8];
  {
    const int rr = lane & 31, kh = lane >> 5;
    const int g = rr & 3, q = rr >> 2;
    const int u = w * 8 + 4 * (q & 1) + (q >> 1);
    const int row = g * 64 + u;
#pragma unroll
    for (int kc = 0; kc < 8; ++kc) {
      int k0 = kc * 16 + kh * 8;
      const float* src = (k0 < 64) ? (Wih + row * 64 + k0)
                                   : (Whh + row * 64 + (k0 - 64));
      float4 f0 = *(const float4*)(src);
      float4 f1 = *(const float4*)(src + 4);
      U8 a;
      a.u[0] = cvt_pk_bf16(f0.x, f0.y); a.u[1] = cvt_pk_bf16(f0.z, f0.w);
      a.u[2] = cvt_pk_bf16(f1.x, f1.y); a.u[3] = cvt_pk_bf16(f1.z, f1.w);
      Af[kc] = a.v;
    }
  }

  const int s   = lane & 31;           // gate-phase / B-col sample
  const int hi  = lane >> 5;
  const int sx3 = (s & 7) << 4;        // 128B-row granule XOR
  const int u0  = w * 8 + 4 * hi;      // 4 consecutive units
  // precomputed short-offsets within a 128B row
  int rofs[4];
#pragma unroll
  for (int kc = 0; kc < 4; ++kc)
    rofs[kc] = s * 64 + (((kc * 32 + hi * 16) ^ sx3) >> 1);
  const int hofs = s * 64 + (((u0 * 2) ^ sx3) >> 1);

  // stage x for timestep ts, samples [sb, sb+8): 1 wave-load, 1KB linear dest.
  // Source granule permute gl^(s&7) reproduces the read-side XOR (rule #21).
  auto stage_x = [&](int ts, int sb) {
    int s_l  = sb + (lane >> 3);
    int gl   = lane & 7;
    int nid  = sh_meta[s_l][ts] & 0xffff;
    int perm = gl ^ (s_l & 7);
    __builtin_amdgcn_global_load_lds(
        (const __attribute__((address_space(1))) unsigned*)
            (fb + (size_t)nid * 32 + perm * 4),
        (__attribute__((address_space(3))) unsigned*)
            (&xq[(ts & 7) * 2048 + sb * 64]),
        16, 0, 0);
  };

  float c4[4] = {0.f, 0.f, 0.f, 0.f};
  float pooled[4][NR] = {};

  __syncthreads();                     // meta + hb ready (needed by stage_x)
  const int len_s = sh_len[s];
  const int tmax  = sh_len[0];         // block max (descending sort)

  {  // prologue: stage chunk 0 (slots 0..3); wave w -> ts = w>>1, 2 loads
    int ts  = w >> 1;
    int sb0 = (w & 1) * 16;
    stage_x(ts, sb0);
    stage_x(ts, sb0 + 8);
  }
  __syncthreads();                     // drain (own) + cross-wave visibility

#pragma unroll 1
  for (int t = 0; t < tmax; ++t) {
    // issue next 4-step chunk at t%4==3 (used from t+1): drain at this
    // phase's end-barrier hides under this phase's compute.
    if ((t & 3) == 3) {
      int T = t + 1;                   // T % 4 == 0
      if (T < tmax) {
        int ts  = T + (w >> 1);
        int sb0 = (w & 1) * 16;
        stage_x(ts, sb0);
        stage_x(ts, sb0 + 8);
      }
    }

    const short* xp = &xq[(t & 7) * 2048];
    const short* hp = &hb[(t & 1) * 2048];
    f32x16 acc = {};
#pragma unroll
    for (int kc = 0; kc < 4; ++kc) {
      bf16x8 b = *(const bf16x8*)(&xp[rofs[kc]]);
      acc = __builtin_amdgcn_mfma_f32_32x32x16_bf16(Af[kc], b, acc, 0, 0, 0);
    }
#pragma unroll
    for (int kc = 0; kc < 4; ++kc) {
      bf16x8 b = *(const bf16x8*)(&hp[rofs[kc]]);
      acc = __builtin_amdgcn_mfma_f32_32x32x16_bf16(Af[kc + 4], b, acc, 0, 0, 0);
    }

    int pk = sh_meta[s][t];
    float wv = (t < len_s) ? sh_w[s][t] : 0.f;
    int rl = pk >> 16;
    float h4[4];
#pragma unroll
    for (int p = 0; p < 4; ++p) {
      float gi = fsig(acc[4 * p + 0]);
      float gf = fsig(acc[4 * p + 1]);
      float gg = ftanh_(acc[4 * p + 2]);
      float go = fsig(acc[4 * p + 3]);
      float cc = gf * c4[p] + gi * gg;
      c4[p] = cc;
      h4[p] = go * ftanh_(cc);
    }
#pragma unroll
    for (int r = 0; r < NR; ++r) {
      float mr = (rl == r) ? wv : 0.f;
      pooled[0][r] += mr * h4[0]; pooled[1][r] += mr * h4[1];
      pooled[2][r] += mr * h4[2]; pooled[3][r] += mr * h4[3];
    }

    *(uint2*)&hb[((t & 1) ^ 1) * 2048 + hofs] =
        make_uint2(cvt_pk_bf16(h4[0], h4[1]), cvt_pk_bf16(h4[2], h4[3]));
    __syncthreads();                   // h(t+1) + (every 4th) staged x ready
  }

  // ---- fused projection epilogue: proj = sum_r pooled_r @ W_r ----
  // pb aliases xq (main loop done). Two pb buffers -> 2 relations per phase.
  short* pb = xq;                      // [2][32][136] shorts
  f32x16 pacc = {};
  const bool mw = (w < 4);             // MFMA waves; wave w owns out rows w*32..+31
#pragma unroll
  for (int rr = 0; rr < 12; rr += 2) {
#pragma unroll
    for (int p = 0; p < 2; ++p) {
      int r = rr + p;
      if (r < NR) {
        float p0 = pooled[0][r], p1 = pooled[1][r];
        float p2 = pooled[2][r], p3 = pooled[3][r];
        unsigned h0 = cvt_pk_bf16(p0, p1), h1 = cvt_pk_bf16(p2, p3);
        float l0 = p0 - __uint_as_float(h0 << 16);
        float l1 = p1 - __uint_as_float(h0 & 0xffff0000u);
        float l2 = p2 - __uint_as_float(h1 << 16);
        float l3 = p3 - __uint_as_float(h1 & 0xffff0000u);
        unsigned g0 = cvt_pk_bf16(l0, l1), g1 = cvt_pk_bf16(l2, l3);
        *(uint2*)&pb[p * 4352 + s * 136 + u0]      = make_uint2(h0, h1);
        *(uint2*)&pb[p * 4352 + s * 136 + 64 + u0] = make_uint2(g0, g1);
      }
    }
    __syncthreads();
    if (mw) {
#pragma unroll
      for (int p = 0; p < 2; ++p) {
        int r = rr + p;
        if (r < NR) {
#pragma unroll
          for (int kc = 0; kc < 4; ++kc) {
            int fi = ((r * 4 + w) * 4 + kc) * 2;
            U8 ah, al;
            *(uint4*)ah.u = *(const uint4*)(wt2 + (size_t)fi * 256 + lane * 4);
            *(uint4*)al.u = *(const uint4*)(wt2 + (size_t)(fi + 1) * 256 + lane * 4);
            bf16x8 bh = *(const bf16x8*)(&pb[p * 4352 + s * 136 + kc * 16 + hi * 8]);
            bf16x8 bl = *(const bf16x8*)(&pb[p * 4352 + s * 136 + 64 + kc * 16 + hi * 8]);
            pacc = __builtin_amdgcn_mfma_f32_32x32x16_bf16(ah.v, bh, pacc, 0, 0, 0);
            pacc = __builtin_amdgcn_mfma_f32_32x32x16_bf16(ah.v, bl, pacc, 0, 0, 0);
            pacc = __builtin_amdgcn_mfma_f32_32x32x16_bf16(al.v, bh, pacc, 0, 0, 0);
            pacc = __builtin_amdgcn_mfma_f32_32x32x16_bf16(al.v, bl, pacc, 0, 0, 0);
          }
        }
      }
    }
    __syncthreads();
  }

  if (mw && (sbase + s) < cnt) {
    int nd = sh_nodes[s];
    float* dst = out + (size_t)nd * OUTD + w * 32;
#pragma unroll
    for (int j = 0; j < 16; ++j) {
      int m = (j & 3) + 8 * (j >> 2) + 4 * hi;
      atomicAdd(dst + m, pacc[j]);
    }
  }
}

__global__ void relu_kernel(float4* __restrict__ out, int n4) {
  int i = blockIdx.x * 256 + threadIdx.x;
  if (i < n4) {
    float4 v = out[i];
    v.x = fmaxf(v.x, 0.f); v.y = fmaxf(v.y, 0.f);
    v.z = fmaxf(v.z, 0.f); v.w = fmaxf(v.w, 0.f);
    out[i] = v;
  }
}

extern "C" void kernel_launch(void* const* d_in, const int* in_sizes, int n_in,
                              void* d_out, int out_size, void* d_ws, size_t ws_size,
                              hipStream_t stream) {
  const int*   nbr   = (const int*)d_in[0];
  const int*   lens  = (const int*)d_in[1];
  const int*   rels  = (const int*)d_in[2];
  const int*   nodes = (const int*)d_in[3];
  const float* adjw  = (const float*)d_in[4];
  const float* feat  = (const float*)d_in[5];
  const float* Wih   = (const float*)d_in[6];
  const float* Whh   = (const float*)d_in[7];
  const float* Wr    = (const float*)d_in[8];
  float* out = (float*)d_out;

  hipMemsetAsync(d_out, 0, (size_t)NS * OUTD * sizeof(float), stream);

  // ws layout: wt2 [0,360448) | fb bf16 feat [360448, 6760448) |
  //            ord [6760448, 6960448) | cnt/cur [6960448, +256)
  unsigned* wt2 = (unsigned*)d_ws;
  unsigned* fb  = (unsigned*)((char*)d_ws + 360448);
  int*      ord = (int*)((char*)d_ws + 6760448);
  int*      cnt = (int*)((char*)d_ws + 6960448);
  int*      cur = cnt + 32;

  wprep_kernel<<<NR, 256, 0, stream>>>(Wr, wt2);
  fprep_kernel<<<(NS * IND / 2 + 255) / 256, 256, 0, stream>>>(feat, fb);
  zero_cnt_kernel<<<1, 64, 0, stream>>>(cnt);
  hist_kernel<<<(NS + 255) / 256, 256, 0, stream>>>(lens, cnt);
  prefix_kernel<<<1, 64, 0, stream>>>(cnt, cur);
  scatter_kernel<<<(NS + 255) / 256, 256, 0, stream>>>(lens, cur, ord);

  lstm_mfma_kernel<<<(NS + 31) / 32, 512, 0, stream>>>(
      fb, nbr, lens, rels, adjw, Wih, Whh, ord, nodes, wt2, out, 0, NS);

  relu_kernel<<<(NS * OUTD / 4 + 255) / 256, 256, 0, stream>>>(
      (float4*)out, NS * OUTD / 4);
}

// Round 12
// 313.652 us; speedup vs baseline: 3.9655x; 1.0006x over previous
//
#include <hip/hip_runtime.h>

#define NS   50000
#define LSEQ 32
#define IND  64
#define HIDN 64
#define OUTD 128
#define NR   11

using bf16x8  = __attribute__((ext_vector_type(8))) short;
using f32x16  = __attribute__((ext_vector_type(16))) float;

union U8 { bf16x8 v; unsigned u[4]; uint2 d[2]; };

__device__ __forceinline__ unsigned cvt_pk_bf16(float a, float b) {
  unsigned r;
  asm volatile("v_cvt_pk_bf16_f32 %0, %1, %2" : "=v"(r) : "v"(a), "v"(b));
  return r;  // r[15:0] = bf16(a), r[31:16] = bf16(b)
}
__device__ __forceinline__ float fsig(float x) {
  return __builtin_amdgcn_rcpf(1.f + __expf(-x));
}
__device__ __forceinline__ float ftanh_(float x) {
  return 1.f - 2.f * __builtin_amdgcn_rcpf(__expf(2.f * x) + 1.f);
}

// ---------------- feature table -> bf16 (halves gather traffic) ------------
__global__ __launch_bounds__(256) void fprep_kernel(
    const float* __restrict__ f, unsigned* __restrict__ fb) {
  int i = blockIdx.x * 256 + threadIdx.x;      // uint index (2 floats)
  if (i < NS * IND / 2) {
    float2 v = ((const float2*)f)[i];
    fb[i] = cvt_pk_bf16(v.x, v.y);
  }
}

// ---------------- length sort (descending), LDS-binned ---------------------
__global__ void zero_cnt_kernel(int* cnt) {
  if (threadIdx.x < 64) cnt[threadIdx.x] = 0;  // cnt[32] + cur[32]
}
__global__ __launch_bounds__(256) void hist_kernel(
    const int* __restrict__ lens, int* __restrict__ cnt) {
  __shared__ int lc[32];
  int t = threadIdx.x;
  if (t < 32) lc[t] = 0;
  __syncthreads();
  int s = blockIdx.x * 256 + t;
  if (s < NS) atomicAdd(&lc[32 - lens[s]], 1);
  __syncthreads();
  if (t < 32 && lc[t]) atomicAdd(&cnt[t], lc[t]);
}
__global__ void prefix_kernel(const int* __restrict__ cnt, int* __restrict__ cur) {
  if (threadIdx.x == 0) {
    int sum = 0;
    for (int b = 0; b < 32; ++b) { cur[b] = sum; sum += cnt[b]; }
  }
}
__global__ __launch_bounds__(256) void scatter_kernel(
    const int* __restrict__ lens, int* __restrict__ cur, int* __restrict__ ord) {
  __shared__ int lc[32], lb[32];
  int t = threadIdx.x;
  if (t < 32) lc[t] = 0;
  __syncthreads();
  int s = blockIdx.x * 256 + t;
  int rank = 0, bin = 0;
  if (s < NS) {
    bin = 32 - lens[s];
    rank = atomicAdd(&lc[bin], 1);      // LDS atomic (fast)
  }
  __syncthreads();
  if (t < 32 && lc[t]) lb[t] = atomicAdd(&cur[t], lc[t]);  // 32/block global
  __syncthreads();
  if (s < NS) ord[lb[bin] + rank] = s;
}

// ---------------------------------------------------------------------------
// Prep: Wr[11][64][128] f32 -> wt2: per-lane-major A fragments for the fused
// projection. frag_idx = ((r*4+nt)*4+kc)*2+pl; u32 offset = frag_idx*256 +
// lane*4; each 16B = W^T(pl)[row=nt*32+(lane&31)][k0..k0+7], k0=kc*16+(lane>>5)*8.
// ---------------------------------------------------------------------------
__global__ __launch_bounds__(256) void wprep_kernel(
    const float* __restrict__ Wr, unsigned* __restrict__ wt2)
{
  __shared__ float wl[64 * 128];
  const int r = blockIdx.x;
  for (int i = threadIdx.x; i < 64 * 128; i += 256)
    wl[i] = Wr[r * 64 * 128 + i];
  __syncthreads();
  for (int idx = threadIdx.x; idx < 2048; idx += 256) {
    int lane = idx & 63;
    int pl   = (idx >> 6) & 1;
    int kc   = (idx >> 7) & 3;
    int nt   = (idx >> 9) & 3;
    int row  = nt * 32 + (lane & 31);          // out index o
    int k0   = kc * 16 + (lane >> 5) * 8;      // hidden-unit k
    unsigned o4[4];
#pragma unroll
    for (int jp = 0; jp < 4; ++jp) {
      float a = wl[(k0 + jp * 2) * 128 + row];      // W[k][o]
      float b = wl[(k0 + jp * 2 + 1) * 128 + row];
      unsigned h = cvt_pk_bf16(a, b);
      if (pl) {
        float la = a - __uint_as_float(h << 16);
        float lb = b - __uint_as_float(h & 0xffff0000u);
        h = cvt_pk_bf16(la, lb);
      }
      o4[jp] = h;
    }
    size_t dst = (size_t)(((r * 4 + nt) * 4 + kc) * 2 + pl) * 256 + lane * 4;
    *(uint4*)(wt2 + dst) = *(uint4*)o4;
  }
}

// ---------------------------------------------------------------------------
// K1: FULLY FUSED gather + bf16-MFMA LSTM + relation pooling + projection +
// atomic scatter. 512 thr / 8 waves / 32 samples, length-sorted blocks.
// R12 change (isolated): xq ring 8 -> 4 slots, 2-step staging chunks issued
// at odd phases (same vmem-free-phase property); xq+hb folded into one arena
// so the epilogue pb alias fits. LDS 49.7KB -> 33.3KB -> 4 blocks/CU.
// ---------------------------------------------------------------------------
__global__ __launch_bounds__(512, 4) void lstm_mfma_kernel(
    const unsigned* __restrict__ fb, const int* __restrict__ nbr,
    const int* __restrict__ lens, const int* __restrict__ rels,
    const float* __restrict__ adjw, const float* __restrict__ Wih,
    const float* __restrict__ Whh, const int* __restrict__ ord,
    const int* __restrict__ nodes, const unsigned* __restrict__ wt2,
    float* __restrict__ out, int s0, int cnt)
{
  // arena: [0,8192) xq = 4 slots x [32 s][128B x]; [8192,12288) hb = 2 bufs.
  // Epilogue aliases arena[0,8704) as pb (2 x [32 s][136 shorts]).
  __shared__ __align__(16) short arena[12288];     // 24KB
  __shared__ float sh_w[32][33];
  __shared__ int   sh_meta[32][33];    // rel<<16 | nbr (nbr < 2^16)
  __shared__ int   sh_len[32];
  __shared__ int   sh_nodes[32];

  const int tid   = threadIdx.x;
  const int lane  = tid & 63;
  const int w     = tid >> 6;
  const int sbase = blockIdx.x * 32;

  for (int i = tid; i < 32 * 32; i += 512) {
    int ss = i >> 5, l = i & 31;
    int gp = sbase + ss;
    bool ok = gp < cnt;
    int gs = ok ? ord[s0 + gp] : 0;
    size_t off = (size_t)gs * LSEQ + l;
    sh_w[ss][l]    = ok ? adjw[off] : 0.f;
    sh_meta[ss][l] = ok ? ((rels[off] << 16) | nbr[off]) : 0;
  }
  if (tid < 32) {
    int gp = sbase + tid;
    bool ok = gp < cnt;
    int gs = ok ? ord[s0 + gp] : 0;
    sh_len[tid]   = ok ? lens[gs] : 0;
    sh_nodes[tid] = ok ? nodes[gs] : 0;
  }
  for (int i = tid; i < 2 * 32 * 64; i += 512) arena[8192 + i] = 0;  // h(0)=0

  // stationary A fragments (gate-permuted weight rows, bf16)
  bf16x8 Af[8];
  {
    const int rr = lane & 31, kh = lane >> 5;
    const int g = rr & 3, q = rr >> 2;
    const int u = w * 8 + 4 * (q & 1) + (q >> 1);
    const int row = g * 64 + u;
#pragma unroll
    for (int kc = 0; kc < 8; ++kc) {
      int k0 = kc * 16 + kh * 8;
      const float* src = (k0 < 64) ? (Wih + row * 64 + k0)
                                   : (Whh + row * 64 + (k0 - 64));
      float4 f0 = *(const float4*)(src);
      float4 f1 = *(const float4*)(src + 4);
      U8 a;
      a.u[0] = cvt_pk_bf16(f0.x, f0.y); a.u[1] = cvt_pk_bf16(f0.z, f0.w);
      a.u[2] = cvt_pk_bf16(f1.x, f1.y); a.u[3] = cvt_pk_bf16(f1.z, f1.w);
      Af[kc] = a.v;
    }
  }

  const int s   = lane & 31;           // gate-phase / B-col sample
  const int hi  = lane >> 5;
  const int sx3 = (s & 7) << 4;        // 128B-row granule XOR
  const int u0  = w * 8 + 4 * hi;      // 4 consecutive units
  int rofs[4];
#pragma unroll
  for (int kc = 0; kc < 4; ++kc)
    rofs[kc] = s * 64 + (((kc * 32 + hi * 16) ^ sx3) >> 1);
  const int hofs = s * 64 + (((u0 * 2) ^ sx3) >> 1);

  // stage x for timestep ts, samples [sb, sb+8): 1 wave-load, 1KB linear dest.
  // Source granule permute gl^(s&7) reproduces the read-side XOR (rule #21).
  auto stage_x = [&](int ts, int sb) {
    int s_l  = sb + (lane >> 3);
    int gl   = lane & 7;
    int nid  = sh_meta[s_l][ts] & 0xffff;
    int perm = gl ^ (s_l & 7);
    __builtin_amdgcn_global_load_lds(
        (const __attribute__((address_space(1))) unsigned*)
            (fb + (size_t)nid * 32 + perm * 4),
        (__attribute__((address_space(3))) unsigned*)
            (&arena[(ts & 3) * 2048 + sb * 64]),
        16, 0, 0);
  };

  float c4[4] = {0.f, 0.f, 0.f, 0.f};
  float pooled[4][NR] = {};

  __syncthreads();                     // meta + hb ready (needed by stage_x)
  const int len_s = sh_len[s];
  const int tmax  = sh_len[0];         // block max (descending sort)

  {  // prologue: stage chunk {0,1}; wave w -> ts = w>>2, sb = (w&3)*8
    int ts = w >> 2;
    if (ts < tmax) stage_x(ts, (w & 3) * 8);
  }
  __syncthreads();                     // drain (own) + cross-wave visibility

#pragma unroll 1
  for (int t = 0; t < tmax; ++t) {
    // issue next 2-step chunk at odd t (used from t+1): slots (t+1)&3 and
    // (t+2)&3 are both retired (read at t-3 / t-2); drain hides in this phase.
    if ((t & 1) == 1 && t + 1 < tmax) {
      int ts = t + 1 + (w >> 2);
      if (ts < tmax) stage_x(ts, (w & 3) * 8);
    }

    const short* xp = &arena[(t & 3) * 2048];
    const short* hp = &arena[8192 + (t & 1) * 2048];
    f32x16 acc = {};
#pragma unroll
    for (int kc = 0; kc < 4; ++kc) {
      bf16x8 b = *(const bf16x8*)(&xp[rofs[kc]]);
      acc = __builtin_amdgcn_mfma_f32_32x32x16_bf16(Af[kc], b, acc, 0, 0, 0);
    }
#pragma unroll
    for (int kc = 0; kc < 4; ++kc) {
      bf16x8 b = *(const bf16x8*)(&hp[rofs[kc]]);
      acc = __builtin_amdgcn_mfma_f32_32x32x16_bf16(Af[kc + 4], b, acc, 0, 0, 0);
    }

    int pk = sh_meta[s][t];
    float wv = (t < len_s) ? sh_w[s][t] : 0.f;
    int rl = pk >> 16;
    float h4[4];
#pragma unroll
    for (int p = 0; p < 4; ++p) {
      float gi = fsig(acc[4 * p + 0]);
      float gf = fsig(acc[4 * p + 1]);
      float gg = ftanh_(acc[4 * p + 2]);
      float go = fsig(acc[4 * p + 3]);
      float cc = gf * c4[p] + gi * gg;
      c4[p] = cc;
      h4[p] = go * ftanh_(cc);
    }
#pragma unroll
    for (int r = 0; r < NR; ++r) {
      float mr = (rl == r) ? wv : 0.f;
      pooled[0][r] += mr * h4[0]; pooled[1][r] += mr * h4[1];
      pooled[2][r] += mr * h4[2]; pooled[3][r] += mr * h4[3];
    }

    *(uint2*)&arena[8192 + ((t & 1) ^ 1) * 2048 + hofs] =
        make_uint2(cvt_pk_bf16(h4[0], h4[1]), cvt_pk_bf16(h4[2], h4[3]));
    __syncthreads();                   // h(t+1) + (every 2nd) staged x ready
  }

  // ---- fused projection epilogue: proj = sum_r pooled_r @ W_r ----
  // pb aliases arena (main loop done). Two pb buffers -> 2 relations/phase.
  short* pb = arena;                   // [2][32][136] shorts = 17408B
  f32x16 pacc = {};
  const bool mw = (w < 4);             // MFMA waves; wave w owns out rows w*32..+31
#pragma unroll
  for (int rr = 0; rr < 12; rr += 2) {
#pragma unroll
    for (int p = 0; p < 2; ++p) {
      int r = rr + p;
      if (r < NR) {
        float p0 = pooled[0][r], p1 = pooled[1][r];
        float p2 = pooled[2][r], p3 = pooled[3][r];
        unsigned h0 = cvt_pk_bf16(p0, p1), h1 = cvt_pk_bf16(p2, p3);
        float l0 = p0 - __uint_as_float(h0 << 16);
        float l1 = p1 - __uint_as_float(h0 & 0xffff0000u);
        float l2 = p2 - __uint_as_float(h1 << 16);
        float l3 = p3 - __uint_as_float(h1 & 0xffff0000u);
        unsigned g0 = cvt_pk_bf16(l0, l1), g1 = cvt_pk_bf16(l2, l3);
        *(uint2*)&pb[p * 4352 + s * 136 + u0]      = make_uint2(h0, h1);
        *(uint2*)&pb[p * 4352 + s * 136 + 64 + u0] = make_uint2(g0, g1);
      }
    }
    __syncthreads();
    if (mw) {
#pragma unroll
      for (int p = 0; p < 2; ++p) {
        int r = rr + p;
        if (r < NR) {
#pragma unroll
          for (int kc = 0; kc < 4; ++kc) {
            int fi = ((r * 4 + w) * 4 + kc) * 2;
            U8 ah, al;
            *(uint4*)ah.u = *(const uint4*)(wt2 + (size_t)fi * 256 + lane * 4);
            *(uint4*)al.u = *(const uint4*)(wt2 + (size_t)(fi + 1) * 256 + lane * 4);
            bf16x8 bh = *(const bf16x8*)(&pb[p * 4352 + s * 136 + kc * 16 + hi * 8]);
            bf16x8 bl = *(const bf16x8*)(&pb[p * 4352 + s * 136 + 64 + kc * 16 + hi * 8]);
            pacc = __builtin_amdgcn_mfma_f32_32x32x16_bf16(ah.v, bh, pacc, 0, 0, 0);
            pacc = __builtin_amdgcn_mfma_f32_32x32x16_bf16(ah.v, bl, pacc, 0, 0, 0);
            pacc = __builtin_amdgcn_mfma_f32_32x32x16_bf16(al.v, bh, pacc, 0, 0, 0);
            pacc = __builtin_amdgcn_mfma_f32_32x32x16_bf16(al.v, bl, pacc, 0, 0, 0);
          }
        }
      }
    }
    __syncthreads();
  }

  if (mw && (sbase + s) < cnt) {
    int nd = sh_nodes[s];
    float* dst = out + (size_t)nd * OUTD + w * 32;
#pragma unroll
    for (int j = 0; j < 16; ++j) {
      int m = (j & 3) + 8 * (j >> 2) + 4 * hi;
      atomicAdd(dst + m, pacc[j]);
    }
  }
}

__global__ void relu_kernel(float4* __restrict__ out, int n4) {
  int i = blockIdx.x * 256 + threadIdx.x;
  if (i < n4) {
    float4 v = out[i];
    v.x = fmaxf(v.x, 0.f); v.y = fmaxf(v.y, 0.f);
    v.z = fmaxf(v.z, 0.f); v.w = fmaxf(v.w, 0.f);
    out[i] = v;
  }
}

extern "C" void kernel_launch(void* const* d_in, const int* in_sizes, int n_in,
                              void* d_out, int out_size, void* d_ws, size_t ws_size,
                              hipStream_t stream) {
  const int*   nbr   = (const int*)d_in[0];
  const int*   lens  = (const int*)d_in[1];
  const int*   rels  = (const int*)d_in[2];
  const int*   nodes = (const int*)d_in[3];
  const float* adjw  = (const float*)d_in[4];
  const float* feat  = (const float*)d_in[5];
  const float* Wih   = (const float*)d_in[6];
  const float* Whh   = (const float*)d_in[7];
  const float* Wr    = (const float*)d_in[8];
  float* out = (float*)d_out;

  hipMemsetAsync(d_out, 0, (size_t)NS * OUTD * sizeof(float), stream);

  // ws layout: wt2 [0,360448) | fb bf16 feat [360448, 6760448) |
  //            ord [6760448, 6960448) | cnt/cur [6960448, +256)
  unsigned* wt2 = (unsigned*)d_ws;
  unsigned* fb  = (unsigned*)((char*)d_ws + 360448);
  int*      ord = (int*)((char*)d_ws + 6760448);
  int*      cnt = (int*)((char*)d_ws + 6960448);
  int*      cur = cnt + 32;

  wprep_kernel<<<NR, 256, 0, stream>>>(Wr, wt2);
  fprep_kernel<<<(NS * IND / 2 + 255) / 256, 256, 0, stream>>>(feat, fb);
  zero_cnt_kernel<<<1, 64, 0, stream>>>(cnt);
  hist_kernel<<<(NS + 255) / 256, 256, 0, stream>>>(lens, cnt);
  prefix_kernel<<<1, 64, 0, stream>>>(cnt, cur);
  scatter_kernel<<<(NS + 255) / 256, 256, 0, stream>>>(lens, cur, ord);

  lstm_mfma_kernel<<<(NS + 31) / 32, 512, 0, stream>>>(
      fb, nbr, lens, rels, adjw, Wih, Whh, ord, nodes, wt2, out, 0, NS);

  relu_kernel<<<(NS * OUTD / 4 + 255) / 256, 256, 0, stream>>>(
      (float4*)out, NS * OUTD / 4);
}